// Round 1
// baseline (617.806 us; speedup 1.0000x reference)
//
#include <hip/hip_runtime.h>
#include <math.h>

#define BB 64
#define TT 256
#define NVV 20000
#define DEG 8
#define EE 128
#define NBUCKET 288
#define HID 100
#define H2 50

// ---------------- workspace layout (floats) ----------------
constexpr int OFF_STATS   = 0;      // 4: sum, sumsq, cnt, pad
constexpr int OFF_CDIST   = 4;      // 100
constexpr int OFF_CDIRX   = 104;    // 100
constexpr int OFF_CDIRY   = 204;    // 100
constexpr int OFF_BASE    = 304;    // 100 (om_b1 + dist_b@W1d + dir_b@W1r)
constexpr int OFF_V25     = 404;    // 25
constexpr int OFF_C25     = 429;    // 25 (tt_b@ob_W1 + ob_b1)
constexpr int OFF_OBZ     = 454;    // 1
constexpr int OFF_DESTPRE = 456;    // B*HID = 6400
constexpr int OFF_WFUSED  = 6856;   // E*HID = 12800
constexpr size_t NROW     = (size_t)BB * TT;          // 16384
constexpr size_t OFF_Q    = 19656;
constexpr size_t OFF_K    = OFF_Q + NROW * EE;        // +2097152
constexpr size_t OFF_V    = OFF_K + NROW * EE;
constexpr size_t OFF_O    = OFF_V + NROW * EE;
constexpr size_t OFF_H1P  = OFF_O + NROW * EE;        // B*T*HID

// ---------------- zero accumulators ----------------
__global__ void k_zero(float* ws, float* out) {
    if (threadIdx.x < 4) ws[OFF_STATS + threadIdx.x] = 0.f;
    if (threadIdx.x == 0) out[0] = 0.f;
}

// ---------------- precompute small fused vectors ----------------
__global__ void k_prevec(const float* dist_W, const float* dist_b,
                         const float* dir_W, const float* dir_b,
                         const float* tt_W, const float* tt_b,
                         const float* ob_W1, const float* ob_b1,
                         const float* ob_W2, const float* ob_b2,
                         const float* om_W1, const float* om_b1,
                         float* ws) {
    int j = threadIdx.x;
    if (j < HID) {
        float cd = 0.f, cx = 0.f, cy = 0.f, bs = om_b1[j];
        for (int f = 0; f < 50; f++) {
            float w1d = om_W1[(128 + f) * HID + j];
            float w1r = om_W1[(178 + f) * HID + j];
            cd += dist_W[f] * w1d;
            bs += dist_b[f] * w1d + dir_b[f] * w1r;
            cx += dir_W[f] * w1r;
            cy += dir_W[50 + f] * w1r;
        }
        ws[OFF_CDIST + j] = cd; ws[OFF_CDIRX + j] = cx;
        ws[OFF_CDIRY + j] = cy; ws[OFF_BASE + j] = bs;
    }
    if (j < 25) {
        float v = 0.f, c = ob_b1[j];
        for (int i = 0; i < 50; i++) {
            v += tt_W[i] * ob_W1[i * 25 + j];
            c += tt_b[i] * ob_W1[i * 25 + j];
        }
        ws[OFF_V25 + j] = v; ws[OFF_C25 + j] = c;
    }
    if (j == 0) {
        float z = ob_b2[0];
        for (int i = 0; i < 25; i++) z += fmaxf(ob_b1[i], 0.f) * ob_W2[i];
        ws[OFF_OBZ] = z;
    }
}

// ---------------- dest_pre[b] = emb[dest[b]] @ om_W1[228:356] ----------------
__global__ void k_destpre(const int* destinations, const float* emb,
                          const float* om_W1, float* ws) {
    __shared__ float er[EE];
    int b = blockIdx.x;
    int d = destinations[b];
    er[threadIdx.x] = emb[(size_t)d * EE + threadIdx.x];
    __syncthreads();
    int m = threadIdx.x;
    if (m < HID) {
        float acc = 0.f;
        for (int i = 0; i < EE; i++) acc += er[i] * om_W1[(228 + i) * HID + m];
        ws[OFF_DESTPRE + b * HID + m] = acc;
    }
}

// ---------------- Wfused = Wo @ om_W1[0:128]  (128x100) ----------------
__global__ void k_wfused(const float* Wo, const float* om_W1, float* ws) {
    __shared__ float wr[EE];
    int i = blockIdx.x;
    wr[threadIdx.x] = Wo[i * EE + threadIdx.x];
    __syncthreads();
    int m = threadIdx.x;
    if (m < HID) {
        float acc = 0.f;
        for (int j = 0; j < EE; j++) acc += wr[j] * om_W1[j * HID + m];
        ws[OFF_WFUSED + i * HID + m] = acc;
    }
}

// ---------------- QKV projections, 16 rows per block ----------------
__global__ void __launch_bounds__(128) k_qkv(const int* xs, const float* emb,
                      const float* Wq, const float* Wk, const float* Wv,
                      float* ws) {
    __shared__ float xe[16][EE];
    int r0 = blockIdx.x * 16;
    int tid = threadIdx.x;
    for (int r = 0; r < 16; r++) {
        int vid = xs[r0 + r];
        xe[r][tid] = emb[(size_t)vid * EE + tid];
    }
    __syncthreads();
    float* Q = ws + OFF_Q; float* K = ws + OFF_K; float* V = ws + OFF_V;
    const float* Ws[3] = {Wq, Wk, Wv};
    float* Os[3] = {Q, K, V};
    for (int mtx = 0; mtx < 3; mtx++) {
        const float* W = Ws[mtx];
        float acc[16];
        #pragma unroll
        for (int r = 0; r < 16; r++) acc[r] = 0.f;
        for (int i = 0; i < EE; i++) {
            float w = W[i * EE + tid];
            #pragma unroll
            for (int r = 0; r < 16; r++) acc[r] += xe[r][i] * w;
        }
        float* O = Os[mtx];
        for (int r = 0; r < 16; r++) O[(size_t)(r0 + r) * EE + tid] = acc[r];
    }
}

// ---------------- causal attention, one query row per block ----------------
__global__ void __launch_bounds__(128) k_attn(const int* lengths, float* ws) {
    int blk = blockIdx.x;
    int b = blk >> 8;
    int t = blk & 255;
    int len = lengths[b];
    if (t >= len - 1) return;   // hidden unused there
    __shared__ float q4s[EE];
    __shared__ float sc[TT];
    __shared__ float red[128];
    int tid = threadIdx.x;
    const float* Q = ws + OFF_Q; const float* K = ws + OFF_K; const float* V = ws + OFF_V;
    float* O = ws + OFF_O;
    size_t row = (size_t)blk * EE;
    q4s[tid] = Q[row + tid];
    __syncthreads();
    const float4* q4 = (const float4*)q4s;
    float lmax = -1e30f;
    #pragma unroll
    for (int h = 0; h < 2; h++) {
        int kk = tid + h * 128;
        if (kk <= t) {
            const float4* kr = (const float4*)(K + ((size_t)(b * TT + kk)) * EE);
            float s = 0.f;
            #pragma unroll
            for (int i = 0; i < EE / 4; i++) {
                float4 a = q4[i]; float4 bb = kr[i];
                s += a.x * bb.x + a.y * bb.y + a.z * bb.z + a.w * bb.w;
            }
            s *= 0.08838834764831845f;   // 1/sqrt(128)
            sc[kk] = s;
            lmax = fmaxf(lmax, s);
        }
    }
    red[tid] = lmax; __syncthreads();
    for (int s = 64; s > 0; s >>= 1) {
        if (tid < s) red[tid] = fmaxf(red[tid], red[tid + s]);
        __syncthreads();
    }
    float m = red[0];
    __syncthreads();
    float lsum = 0.f;
    #pragma unroll
    for (int h = 0; h < 2; h++) {
        int kk = tid + h * 128;
        if (kk <= t) { float p = __expf(sc[kk] - m); sc[kk] = p; lsum += p; }
    }
    red[tid] = lsum; __syncthreads();
    for (int s = 64; s > 0; s >>= 1) {
        if (tid < s) red[tid] += red[tid + s];
        __syncthreads();
    }
    float inv = 1.f / red[0];
    float acc = 0.f;
    for (int kk = 0; kk <= t; kk++)
        acc += sc[kk] * V[((size_t)(b * TT + kk)) * EE + tid];
    O[row + tid] = acc * inv;
}

// ---------------- h1pre = O @ Wfused + base + dest_pre[b], 16 rows/block ----------------
__global__ void __launch_bounds__(128) k_h1pre(float* ws) {
    __shared__ float ox[16][EE];
    int r0 = blockIdx.x * 16;
    int tid = threadIdx.x;
    const float* O = ws + OFF_O;
    for (int r = 0; r < 16; r++) ox[r][tid] = O[(size_t)(r0 + r) * EE + tid];
    __syncthreads();
    int b = r0 >> 8;
    int m = tid;
    if (m < HID) {
        float acc[16];
        #pragma unroll
        for (int r = 0; r < 16; r++) acc[r] = 0.f;
        const float* WF = ws + OFF_WFUSED;
        for (int i = 0; i < EE; i++) {
            float w = WF[i * HID + m];
            #pragma unroll
            for (int r = 0; r < 16; r++) acc[r] += ox[r][i] * w;
        }
        float add = ws[OFF_BASE + m] + ws[OFF_DESTPRE + b * HID + m];
        float* H = ws + OFF_H1P;
        for (int r = 0; r < 16; r++) H[(size_t)(r0 + r) * HID + m] = acc[r] + add;
    }
}

// ---------------- masked global whitening stats ----------------
__global__ void __launch_bounds__(256) k_stats(const int* xs, const int* lengths, const int* adj,
                        const int* seg, const int* stime, const float* tds,
                        float* ws) {
    int st = *stime;
    float lsum = 0.f, lsq = 0.f, lcnt = 0.f;
    int total = BB * TT * DEG;
    for (int idx = blockIdx.x * blockDim.x + threadIdx.x; idx < total;
         idx += gridDim.x * blockDim.x) {
        int d = idx & 7;
        int bt = idx >> 3;
        int t = bt & 255;
        int b = bt >> 8;
        int len = lengths[b];
        if (t >= len - 1) continue;
        int v = xs[bt];
        int a = adj[v * DEG + d];
        if (a == 0) continue;
        int sg = seg[v * DEG + d];
        float tt = tds[(size_t)sg * NBUCKET + st];
        lsum += tt; lsq += tt * tt; lcnt += 1.f;
    }
    __shared__ float rs[256], rq[256], rc[256];
    int tid = threadIdx.x;
    rs[tid] = lsum; rq[tid] = lsq; rc[tid] = lcnt;
    __syncthreads();
    for (int s = 128; s > 0; s >>= 1) {
        if (tid < s) { rs[tid] += rs[tid + s]; rq[tid] += rq[tid + s]; rc[tid] += rc[tid + s]; }
        __syncthreads();
    }
    if (tid == 0) {
        atomicAdd(&ws[OFF_STATS + 0], rs[0]);
        atomicAdd(&ws[OFF_STATS + 1], rq[0]);
        atomicAdd(&ws[OFF_STATS + 2], rc[0]);
    }
}

// ---------------- per-(b,t): 8 neighbors, MLP, CE, accumulate ----------------
__global__ void __launch_bounds__(256) k_final(
    const int* xs, const int* lengths, const int* xs_actions, const int* destinations,
    const int* adj, const int* seg, const int* stime,
    const float* locations, const float* tds,
    const float* om_W2, const float* om_b2, const float* om_W3, const float* om_b3,
    const float* ob_W2, const float* ob_b2,
    const float* ws, float* out)
{
    int blk = blockIdx.x;
    int b = blk / (TT - 1);
    int t = blk % (TT - 1);
    int len = lengths[b];
    if (t >= len - 1) return;
    int tid = threadIdx.x;
    __shared__ float h1base[HID];
    __shared__ float h1s[DEG][104];
    __shared__ float lg[DEG];
    const float* H = ws + OFF_H1P;
    if (tid < HID) h1base[tid] = H[(size_t)(b * TT + t) * HID + tid];
    float sum = ws[OFF_STATS], sq = ws[OFF_STATS + 1], cnt = ws[OFF_STATS + 2];
    float mean = sum / cnt;
    float var = (sq - cnt * mean * mean) / (cnt - 1.f);
    float sdinv = 1.f / (sqrtf(var) + 1e-6f);
    int v = xs[b * TT + t];
    float cx = locations[2 * v], cy = locations[2 * v + 1];
    int dst = destinations[b];
    float dxl = locations[2 * dst], dyl = locations[2 * dst + 1];
    int g = tid >> 5;
    int lane = tid & 31;
    int a = adj[v * DEG + g];
    int sg = seg[v * DEG + g];
    int st = *stime;
    float ttraw = tds[(size_t)sg * NBUCKET + st];
    float nbx = locations[2 * a], nby = locations[2 * a + 1];
    float dist = (fabsf(nbx - dxl) + fabsf(nby - dyl)) * 100.f;
    float vx = nbx - cx, vy = nby - cy;
    float nrm = sqrtf(vx * vx + vy * vy) + 1e-8f;
    float ux = vx / nrm, uy = vy / nrm;
    float ttn = (ttraw - mean) * sdinv;
    __syncthreads();
    for (int m = lane; m < HID; m += 32) {
        float pre = h1base[m] + dist * ws[OFF_CDIST + m]
                  + ux * ws[OFF_CDIRX + m] + uy * ws[OFF_CDIRY + m];
        h1s[g][m] = fmaxf(pre, 0.f);
    }
    float obp = 0.f;
    if (lane < 25)
        obp = fmaxf(ttn * ws[OFF_V25 + lane] + ws[OFF_C25 + lane], 0.f) * ob_W2[lane];
    #pragma unroll
    for (int o = 16; o > 0; o >>= 1) obp += __shfl_xor(obp, o, 32);
    float ob = (a != 0) ? (obp + ob_b2[0]) : ws[OFF_OBZ];
    __syncthreads();
    float part = 0.f;
    for (int n = lane; n < H2; n += 32) {
        float acc = om_b2[n];
        for (int m = 0; m < HID; m++) acc += h1s[g][m] * om_W2[m * H2 + n];
        part += fmaxf(acc, 0.f) * om_W3[n];
    }
    #pragma unroll
    for (int o = 16; o > 0; o >>= 1) part += __shfl_xor(part, o, 32);
    if (lane == 0) lg[g] = part + om_b3[0] + ob;
    __syncthreads();
    if (tid == 0) {
        int act = xs_actions[b * (TT - 1) + t];
        float mx = -1e30f;
        for (int d = 0; d < DEG; d++) mx = fmaxf(mx, lg[d]);
        float se = 0.f;
        for (int d = 0; d < DEG; d++) se += __expf(lg[d] - mx);
        float nll = mx + __logf(se) - lg[act];
        atomicAdd(out, nll / (float)(len - 1));
    }
}

extern "C" void kernel_launch(void* const* d_in, const int* in_sizes, int n_in,
                              void* d_out, int out_size, void* d_ws, size_t ws_size,
                              hipStream_t stream) {
    const int* xs_padded    = (const int*)d_in[0];
    const int* lengths      = (const int*)d_in[1];
    const int* xs_actions   = (const int*)d_in[2];
    const int* destinations = (const int*)d_in[3];
    const int* adj_list     = (const int*)d_in[4];
    const int* seg_ids      = (const int*)d_in[5];
    const int* start_time   = (const int*)d_in[6];
    const float* locations  = (const float*)d_in[7];
    const float* tds        = (const float*)d_in[8];
    const float* emb        = (const float*)d_in[9];
    const float* Wq         = (const float*)d_in[10];
    const float* Wk         = (const float*)d_in[11];
    const float* Wv         = (const float*)d_in[12];
    const float* Wo         = (const float*)d_in[13];
    const float* dist_W     = (const float*)d_in[14];
    const float* dist_b     = (const float*)d_in[15];
    const float* dir_W      = (const float*)d_in[16];
    const float* dir_b      = (const float*)d_in[17];
    const float* tt_W       = (const float*)d_in[18];
    const float* tt_b       = (const float*)d_in[19];
    const float* ob_W1      = (const float*)d_in[20];
    const float* ob_b1      = (const float*)d_in[21];
    const float* ob_W2      = (const float*)d_in[22];
    const float* ob_b2      = (const float*)d_in[23];
    const float* om_W1      = (const float*)d_in[24];
    const float* om_b1      = (const float*)d_in[25];
    const float* om_W2      = (const float*)d_in[26];
    const float* om_b2      = (const float*)d_in[27];
    const float* om_W3      = (const float*)d_in[28];
    const float* om_b3      = (const float*)d_in[29];
    float* ws  = (float*)d_ws;
    float* out = (float*)d_out;

    k_zero<<<1, 64, 0, stream>>>(ws, out);
    k_prevec<<<1, 128, 0, stream>>>(dist_W, dist_b, dir_W, dir_b, tt_W, tt_b,
                                    ob_W1, ob_b1, ob_W2, ob_b2, om_W1, om_b1, ws);
    k_destpre<<<BB, 128, 0, stream>>>(destinations, emb, om_W1, ws);
    k_wfused<<<EE, 128, 0, stream>>>(Wo, om_W1, ws);
    k_qkv<<<(BB * TT) / 16, 128, 0, stream>>>(xs_padded, emb, Wq, Wk, Wv, ws);
    k_attn<<<BB * TT, 128, 0, stream>>>(lengths, ws);
    k_h1pre<<<(BB * TT) / 16, 128, 0, stream>>>(ws);
    k_stats<<<256, 256, 0, stream>>>(xs_padded, lengths, adj_list, seg_ids,
                                     start_time, tds, ws);
    k_final<<<BB * (TT - 1), 256, 0, stream>>>(
        xs_padded, lengths, xs_actions, destinations, adj_list, seg_ids,
        start_time, locations, tds, om_W2, om_b2, om_W3, om_b3,
        ob_W2, ob_b2, ws, out);
}

// Round 2
// 530.482 us; speedup vs baseline: 1.1646x; 1.1646x over previous
//
#include <hip/hip_runtime.h>
#include <math.h>

#define BB 64
#define TT 256
#define DEG 8
#define EE 128
#define NBUCKET 288
#define HID 100
#define H2 50

// ---------------- workspace layout (floats) ----------------
constexpr size_t OFF_STATS   = 0;        // 4: sum, sumsq, cnt, pad
constexpr size_t OFF_CDIST   = 4;        // 100
constexpr size_t OFF_CDIRX   = 104;      // 100
constexpr size_t OFF_CDIRY   = 204;      // 100
constexpr size_t OFF_BASE    = 304;      // 100
constexpr size_t OFF_V25     = 404;      // 25
constexpr size_t OFF_C25     = 429;      // 25
constexpr size_t OFF_OBZ     = 454;      // 1
constexpr size_t OFF_DESTPRE = 456;      // 64*100
constexpr size_t OFF_WF      = 6856;     // 128*100 (Wo @ om_W1[0:128])
constexpr size_t OFF_WVF     = 19656;    // 128*100 (Wv @ WF)
constexpr size_t OFF_TT      = 32456;    // 16384*8 travel times
constexpr size_t OFF_Q       = 163528;   // 16384*128
constexpr size_t OFF_K       = OFF_Q + 16384 * 128;
constexpr size_t OFF_VP      = OFF_K + 16384 * 128;   // 16384*100
constexpr size_t OFF_H1P     = OFF_VP + 16384 * 100;  // 16384*100

// ---------------- precompute fused vectors (+zero accumulators) ----------------
__global__ void k_prevec(const float* dist_W, const float* dist_b,
                         const float* dir_W, const float* dir_b,
                         const float* tt_W, const float* tt_b,
                         const float* ob_W1, const float* ob_b1,
                         const float* ob_W2, const float* ob_b2,
                         const float* om_W1, const float* om_b1,
                         float* ws, float* out) {
    int j = threadIdx.x;
    if (j < 4) ws[OFF_STATS + j] = 0.f;
    if (j == 0) out[0] = 0.f;
    if (j < HID) {
        float cd = 0.f, cx = 0.f, cy = 0.f, bs = om_b1[j];
        for (int f = 0; f < 50; f++) {
            float w1d = om_W1[(128 + f) * HID + j];
            float w1r = om_W1[(178 + f) * HID + j];
            cd += dist_W[f] * w1d;
            bs += dist_b[f] * w1d + dir_b[f] * w1r;
            cx += dir_W[f] * w1r;
            cy += dir_W[50 + f] * w1r;
        }
        ws[OFF_CDIST + j] = cd; ws[OFF_CDIRX + j] = cx;
        ws[OFF_CDIRY + j] = cy; ws[OFF_BASE + j] = bs;
    }
    if (j < 25) {
        float v = 0.f, c = ob_b1[j];
        for (int i = 0; i < 50; i++) {
            v += tt_W[i] * ob_W1[i * 25 + j];
            c += tt_b[i] * ob_W1[i * 25 + j];
        }
        ws[OFF_V25 + j] = v; ws[OFF_C25 + j] = c;
    }
    if (j == 64) {
        float z = ob_b2[0];
        for (int i = 0; i < 25; i++) z += fmaxf(ob_b1[i], 0.f) * ob_W2[i];
        ws[OFF_OBZ] = z;
    }
}

// ---------------- dest_pre[b] = emb[dest[b]] @ om_W1[228:356] ----------------
__global__ void k_destpre(const int* destinations, const float* emb,
                          const float* om_W1, float* ws) {
    __shared__ float er[EE];
    int b = blockIdx.x;
    int d = destinations[b];
    er[threadIdx.x] = emb[(size_t)d * EE + threadIdx.x];
    __syncthreads();
    int m = threadIdx.x;
    if (m < HID) {
        float acc = 0.f;
        for (int i = 0; i < EE; i++) acc += er[i] * om_W1[(228 + i) * HID + m];
        ws[OFF_DESTPRE + b * HID + m] = acc;
    }
}

// ---------------- WF = Wo @ om_W1[0:128]  (128x100) ----------------
__global__ void k_wfused(const float* Wo, const float* om_W1, float* ws) {
    __shared__ float wr[EE];
    int i = blockIdx.x;
    wr[threadIdx.x] = Wo[i * EE + threadIdx.x];
    __syncthreads();
    int m = threadIdx.x;
    if (m < HID) {
        float acc = 0.f;
        for (int j = 0; j < EE; j++) acc += wr[j] * om_W1[j * HID + m];
        ws[OFF_WF + i * HID + m] = acc;
    }
}

// ---------------- WvF = Wv @ WF  (128x100) ----------------
__global__ void k_wvf(const float* Wv, float* ws) {
    __shared__ float wr[EE];
    int i = blockIdx.x;
    wr[threadIdx.x] = Wv[i * EE + threadIdx.x];
    __syncthreads();
    int m = threadIdx.x;
    if (m < HID) {
        float acc = 0.f;
        const float* WF = ws + OFF_WF;
        for (int j = 0; j < EE; j++) acc += wr[j] * WF[j * HID + m];
        ws[OFF_WVF + i * HID + m] = acc;
    }
}

// ---------------- Q,K (128) and V' (100) projections: tiled GEMM ----------------
// 32 rows/block, 256 threads, 4x4 register tiles.
__global__ void __launch_bounds__(256) k_qkv(const int* xs, const float* emb,
                      const float* Wq, const float* Wk, float* ws) {
    __shared__ float XT[EE][36];   // transposed, padded (36*4=144, 16B-aligned rows)
    __shared__ int vids[32];
    int tid = threadIdx.x;
    int r0 = blockIdx.x * 32;
    if (tid < 32) vids[tid] = xs[r0 + tid];
    __syncthreads();
    for (int c = 0; c < 16; c++) {
        int idx = c * 256 + tid;
        int r = idx >> 7, i = idx & 127;
        XT[i][r] = emb[(size_t)vids[r] * EE + i];
    }
    __syncthreads();
    int cg = tid & 31, rg = tid >> 5;   // cols cg*4.., rows rg*4..
    const float* Wmats[2] = {Wq, Wk};
    float* Omats[2] = {ws + OFF_Q, ws + OFF_K};
    for (int mtx = 0; mtx < 2; mtx++) {
        const float* W = Wmats[mtx];
        float acc[4][4];
        #pragma unroll
        for (int a = 0; a < 4; a++)
            #pragma unroll
            for (int bb = 0; bb < 4; bb++) acc[a][bb] = 0.f;
        #pragma unroll 4
        for (int i = 0; i < EE; i++) {
            float4 av = *(const float4*)&XT[i][rg << 2];
            float4 wv = *(const float4*)&W[i * EE + (cg << 2)];
            acc[0][0] += av.x * wv.x; acc[0][1] += av.x * wv.y; acc[0][2] += av.x * wv.z; acc[0][3] += av.x * wv.w;
            acc[1][0] += av.y * wv.x; acc[1][1] += av.y * wv.y; acc[1][2] += av.y * wv.z; acc[1][3] += av.y * wv.w;
            acc[2][0] += av.z * wv.x; acc[2][1] += av.z * wv.y; acc[2][2] += av.z * wv.z; acc[2][3] += av.z * wv.w;
            acc[3][0] += av.w * wv.x; acc[3][1] += av.w * wv.y; acc[3][2] += av.w * wv.z; acc[3][3] += av.w * wv.w;
        }
        float* O = Omats[mtx];
        #pragma unroll
        for (int j = 0; j < 4; j++)
            *(float4*)&O[(size_t)(r0 + (rg << 2) + j) * EE + (cg << 2)] =
                make_float4(acc[j][0], acc[j][1], acc[j][2], acc[j][3]);
    }
    if (cg < 25) {
        const float* W = ws + OFF_WVF;
        float acc[4][4];
        #pragma unroll
        for (int a = 0; a < 4; a++)
            #pragma unroll
            for (int bb = 0; bb < 4; bb++) acc[a][bb] = 0.f;
        #pragma unroll 4
        for (int i = 0; i < EE; i++) {
            float4 av = *(const float4*)&XT[i][rg << 2];
            float4 wv = *(const float4*)&W[i * HID + (cg << 2)];
            acc[0][0] += av.x * wv.x; acc[0][1] += av.x * wv.y; acc[0][2] += av.x * wv.z; acc[0][3] += av.x * wv.w;
            acc[1][0] += av.y * wv.x; acc[1][1] += av.y * wv.y; acc[1][2] += av.y * wv.z; acc[1][3] += av.y * wv.w;
            acc[2][0] += av.z * wv.x; acc[2][1] += av.z * wv.y; acc[2][2] += av.z * wv.z; acc[2][3] += av.z * wv.w;
            acc[3][0] += av.w * wv.x; acc[3][1] += av.w * wv.y; acc[3][2] += av.w * wv.z; acc[3][3] += av.w * wv.w;
        }
        float* VP = ws + OFF_VP;
        #pragma unroll
        for (int j = 0; j < 4; j++)
            *(float4*)&VP[(size_t)(r0 + (rg << 2) + j) * HID + (cg << 2)] =
                make_float4(acc[j][0], acc[j][1], acc[j][2], acc[j][3]);
    }
}

// ---------------- attention + fused H1P epilogue ----------------
__global__ void __launch_bounds__(128) k_attn(const int* lengths, float* ws) {
    int blk = blockIdx.x;
    int b = blk >> 8;
    int t = blk & 255;
    int len = lengths[b];
    if (t >= len - 1) return;
    __shared__ float q4s[EE];
    __shared__ float sc[TT];
    __shared__ float redm[2], reds[2];
    int tid = threadIdx.x;
    const float* Q = ws + OFF_Q; const float* K = ws + OFF_K;
    const float* VP = ws + OFF_VP;
    q4s[tid] = Q[(size_t)blk * EE + tid];
    __syncthreads();
    const float4* q4 = (const float4*)q4s;
    float lmax = -1e30f;
    #pragma unroll
    for (int h = 0; h < 2; h++) {
        int kk = tid + h * 128;
        if (kk <= t) {
            const float4* kr = (const float4*)(K + ((size_t)(b * TT + kk)) * EE);
            float s = 0.f;
            #pragma unroll 8
            for (int i = 0; i < EE / 4; i++) {
                float4 a = q4[i]; float4 bb = kr[i];
                s += a.x * bb.x + a.y * bb.y + a.z * bb.z + a.w * bb.w;
            }
            s *= 0.08838834764831845f;
            sc[kk] = s;
            lmax = fmaxf(lmax, s);
        }
    }
    #pragma unroll
    for (int o = 32; o > 0; o >>= 1) lmax = fmaxf(lmax, __shfl_xor(lmax, o, 64));
    if ((tid & 63) == 0) redm[tid >> 6] = lmax;
    __syncthreads();
    float m = fmaxf(redm[0], redm[1]);
    float lsum = 0.f;
    #pragma unroll
    for (int h = 0; h < 2; h++) {
        int kk = tid + h * 128;
        if (kk <= t) { float p = __expf(sc[kk] - m); sc[kk] = p; lsum += p; }
    }
    #pragma unroll
    for (int o = 32; o > 0; o >>= 1) lsum += __shfl_xor(lsum, o, 64);
    if ((tid & 63) == 0) reds[tid >> 6] = lsum;
    __syncthreads();
    float inv = 1.f / (reds[0] + reds[1]);
    if (tid < HID) {
        size_t base = (size_t)(b * TT) * HID + tid;
        float a0 = 0.f, a1 = 0.f, a2 = 0.f, a3 = 0.f;
        int kk = 0;
        for (; kk + 4 <= t + 1; kk += 4) {
            a0 += sc[kk]     * VP[base + (size_t)kk * HID];
            a1 += sc[kk + 1] * VP[base + (size_t)(kk + 1) * HID];
            a2 += sc[kk + 2] * VP[base + (size_t)(kk + 2) * HID];
            a3 += sc[kk + 3] * VP[base + (size_t)(kk + 3) * HID];
        }
        for (; kk <= t; kk++) a0 += sc[kk] * VP[base + (size_t)kk * HID];
        float o = (a0 + a1 + a2 + a3) * inv;
        ws[OFF_H1P + (size_t)blk * HID + tid] =
            o + ws[OFF_BASE + tid] + ws[OFF_DESTPRE + b * HID + tid];
    }
}

// ---------------- whitening stats + cache tt gather ----------------
__global__ void __launch_bounds__(256) k_stats(const int* xs, const int* lengths, const int* adj,
                        const int* seg, const int* stime, const float* tds,
                        float* ws) {
    int st = *stime;
    float lsum = 0.f, lsq = 0.f, lcnt = 0.f;
    int total = BB * TT * DEG;
    for (int idx = blockIdx.x * blockDim.x + threadIdx.x; idx < total;
         idx += gridDim.x * blockDim.x) {
        int d = idx & 7;
        int bt = idx >> 3;
        int t = bt & 255;
        int b = bt >> 8;
        int len = lengths[b];
        if (t >= len - 1) continue;
        int v = xs[bt];
        int sg = seg[v * DEG + d];
        float tt = tds[(size_t)sg * NBUCKET + st];
        ws[OFF_TT + idx] = tt;
        int a = adj[v * DEG + d];
        if (a != 0) { lsum += tt; lsq += tt * tt; lcnt += 1.f; }
    }
    __shared__ float rs[256], rq[256], rc[256];
    int tid = threadIdx.x;
    rs[tid] = lsum; rq[tid] = lsq; rc[tid] = lcnt;
    __syncthreads();
    for (int s = 128; s > 0; s >>= 1) {
        if (tid < s) { rs[tid] += rs[tid + s]; rq[tid] += rq[tid + s]; rc[tid] += rc[tid + s]; }
        __syncthreads();
    }
    if (tid == 0) {
        atomicAdd(&ws[OFF_STATS + 0], rs[0]);
        atomicAdd(&ws[OFF_STATS + 1], rq[0]);
        atomicAdd(&ws[OFF_STATS + 2], rc[0]);
    }
}

// ---------------- final: features + h2 GEMM + CE, 4 (b,t) pairs/block ----------------
__global__ void __launch_bounds__(256) k_final(
    const int* xs, const int* lengths, const int* xs_actions, const int* destinations,
    const int* adj, const float* locations,
    const float* om_W2, const float* om_b2, const float* om_W3, const float* om_b3,
    const float* ob_W2, const float* ob_b2,
    const float* ws, float* out)
{
    __shared__ float W2T[H2][104];      // om_W2 transposed, padded
    __shared__ float h1s[4][DEG][104];  // per-wave h1 rows
    __shared__ float nlls[4];
    int tid = threadIdx.x;
    for (int idx = tid; idx < HID * H2; idx += 256) {
        int mm = idx / H2, n = idx - mm * H2;
        W2T[n][mm] = om_W2[idx];
    }
    if (tid < 4) nlls[tid] = 0.f;
    int w = tid >> 6, lane = tid & 63;
    int pi = blockIdx.x * 4 + w;
    int b = pi / (TT - 1), t = pi - b * (TT - 1);
    int len = lengths[b];
    bool valid = (t < len - 1);
    int bt = b * TT + t;
    int r = lane >> 3, li = lane & 7;
    __syncthreads();
    float distv = 0.f, uxv = 0.f, uyv = 0.f, obv = 0.f;
    if (valid) {
        float sum = ws[OFF_STATS], sq = ws[OFF_STATS + 1], cnt = ws[OFF_STATS + 2];
        float mean = sum / cnt;
        float var = (sq - cnt * mean * mean) / (cnt - 1.f);
        float sdinv = 1.f / (sqrtf(var) + 1e-6f);
        if (lane < 8) {
            int v = xs[bt];
            int a = adj[v * DEG + lane];
            float nbx = locations[2 * a], nby = locations[2 * a + 1];
            int dst = destinations[b];
            float dxl = locations[2 * dst], dyl = locations[2 * dst + 1];
            float cxl = locations[2 * v], cyl = locations[2 * v + 1];
            distv = (fabsf(nbx - dxl) + fabsf(nby - dyl)) * 100.f;
            float vx = nbx - cxl, vy = nby - cyl;
            float nrm = sqrtf(vx * vx + vy * vy) + 1e-8f;
            uxv = vx / nrm; uyv = vy / nrm;
            float ttn = (ws[OFF_TT + (size_t)bt * 8 + lane] - mean) * sdinv;
            float obp = 0.f;
            for (int j = 0; j < 25; j++)
                obp += fmaxf(ttn * ws[OFF_V25 + j] + ws[OFF_C25 + j], 0.f) * ob_W2[j];
            obv = (a != 0) ? (obp + ob_b2[0]) : ws[OFF_OBZ];
        }
        distv = __shfl(distv, r, 64);
        uxv   = __shfl(uxv, r, 64);
        uyv   = __shfl(uyv, r, 64);
        obv   = __shfl(obv, r, 64);
        const float* H = ws + OFF_H1P + (size_t)bt * HID;
        for (int mm = li; mm < HID; mm += 8) {
            float pre = H[mm] + distv * ws[OFF_CDIST + mm]
                      + uxv * ws[OFF_CDIRX + mm] + uyv * ws[OFF_CDIRY + mm];
            h1s[w][r][mm] = fmaxf(pre, 0.f);
        }
    }
    __syncthreads();
    if (valid) {
        float acc[7] = {0.f, 0.f, 0.f, 0.f, 0.f, 0.f, 0.f};
        const float4* hv4 = (const float4*)h1s[w][r];
        for (int ks = 0; ks < 25; ks++) {
            float4 h = hv4[ks];
            #pragma unroll
            for (int j = 0; j < 7; j++) {
                int n = li + 8 * j;
                if (n < H2) {
                    float4 wv = *(const float4*)&W2T[n][ks << 2];
                    acc[j] += h.x * wv.x + h.y * wv.y + h.z * wv.z + h.w * wv.w;
                }
            }
        }
        float part = 0.f;
        #pragma unroll
        for (int j = 0; j < 7; j++) {
            int n = li + 8 * j;
            if (n < H2) part += fmaxf(acc[j] + om_b2[n], 0.f) * om_W3[n];
        }
        part += __shfl_xor(part, 1, 8);
        part += __shfl_xor(part, 2, 8);
        part += __shfl_xor(part, 4, 8);
        float logit = part + om_b3[0] + obv;
        float lgv[8];
        float mx = -1e30f;
        #pragma unroll
        for (int d = 0; d < 8; d++) {
            lgv[d] = __shfl(logit, d << 3, 64);
            mx = fmaxf(mx, lgv[d]);
        }
        if (lane == 0) {
            int act = xs_actions[b * (TT - 1) + t];
            float se = 0.f, sel = 0.f;
            #pragma unroll
            for (int d = 0; d < 8; d++) {
                se += __expf(lgv[d] - mx);
                if (d == act) sel = lgv[d];
            }
            float nll = mx + __logf(se) - sel;
            nlls[w] = nll / (float)(len - 1);
        }
    }
    __syncthreads();
    if (tid == 0) {
        atomicAdd(out, nlls[0] + nlls[1] + nlls[2] + nlls[3]);
    }
}

extern "C" void kernel_launch(void* const* d_in, const int* in_sizes, int n_in,
                              void* d_out, int out_size, void* d_ws, size_t ws_size,
                              hipStream_t stream) {
    const int* xs_padded    = (const int*)d_in[0];
    const int* lengths      = (const int*)d_in[1];
    const int* xs_actions   = (const int*)d_in[2];
    const int* destinations = (const int*)d_in[3];
    const int* adj_list     = (const int*)d_in[4];
    const int* seg_ids      = (const int*)d_in[5];
    const int* start_time   = (const int*)d_in[6];
    const float* locations  = (const float*)d_in[7];
    const float* tds        = (const float*)d_in[8];
    const float* emb        = (const float*)d_in[9];
    const float* Wq         = (const float*)d_in[10];
    const float* Wk         = (const float*)d_in[11];
    const float* Wv         = (const float*)d_in[12];
    const float* Wo         = (const float*)d_in[13];
    const float* dist_W     = (const float*)d_in[14];
    const float* dist_b     = (const float*)d_in[15];
    const float* dir_W      = (const float*)d_in[16];
    const float* dir_b      = (const float*)d_in[17];
    const float* tt_W       = (const float*)d_in[18];
    const float* tt_b       = (const float*)d_in[19];
    const float* ob_W1      = (const float*)d_in[20];
    const float* ob_b1      = (const float*)d_in[21];
    const float* ob_W2      = (const float*)d_in[22];
    const float* ob_b2      = (const float*)d_in[23];
    const float* om_W1      = (const float*)d_in[24];
    const float* om_b1      = (const float*)d_in[25];
    const float* om_W2      = (const float*)d_in[26];
    const float* om_b2      = (const float*)d_in[27];
    const float* om_W3      = (const float*)d_in[28];
    const float* om_b3      = (const float*)d_in[29];
    float* ws  = (float*)d_ws;
    float* out = (float*)d_out;

    k_prevec<<<1, 128, 0, stream>>>(dist_W, dist_b, dir_W, dir_b, tt_W, tt_b,
                                    ob_W1, ob_b1, ob_W2, ob_b2, om_W1, om_b1, ws, out);
    k_destpre<<<BB, 128, 0, stream>>>(destinations, emb, om_W1, ws);
    k_wfused<<<EE, 128, 0, stream>>>(Wo, om_W1, ws);
    k_wvf<<<EE, 128, 0, stream>>>(Wv, ws);
    k_qkv<<<(BB * TT) / 32, 256, 0, stream>>>(xs_padded, emb, Wq, Wk, ws);
    k_stats<<<256, 256, 0, stream>>>(xs_padded, lengths, adj_list, seg_ids,
                                     start_time, tds, ws);
    k_attn<<<BB * TT, 128, 0, stream>>>(lengths, ws);
    k_final<<<(BB * (TT - 1)) / 4, 256, 0, stream>>>(
        xs_padded, lengths, xs_actions, destinations, adj_list, locations,
        om_W2, om_b2, om_W3, om_b3, ob_W2, ob_b2, ws, out);
}

// Round 3
// 483.937 us; speedup vs baseline: 1.2766x; 1.0962x over previous
//
#include <hip/hip_runtime.h>
#include <math.h>

#define BB 64
#define TT 256
#define DEG 8
#define EE 128
#define NBUCKET 288
#define HID 100
#define H2 50

// ---------------- workspace layout (floats) ----------------
constexpr size_t OFF_STATS   = 0;        // 4: sum, sumsq, cnt, pad
constexpr size_t OFF_CDIST   = 4;        // 100
constexpr size_t OFF_CDIRX   = 104;      // 100
constexpr size_t OFF_CDIRY   = 204;      // 100
constexpr size_t OFF_BASE    = 304;      // 100
constexpr size_t OFF_V25     = 404;      // 25
constexpr size_t OFF_C25     = 429;      // 25
constexpr size_t OFF_OBZ     = 454;      // 1
constexpr size_t OFF_DESTPRE = 456;      // 64*100
constexpr size_t OFF_WF      = 6856;     // 128*100 (Wo @ om_W1[0:128])
constexpr size_t OFF_TT      = 32456;    // 16384*8 travel times
constexpr size_t OFF_Q       = 163528;   // 16384*128
constexpr size_t OFF_K       = OFF_Q + 16384 * 128;
constexpr size_t OFF_VP      = OFF_K + 16384 * 128;   // 16384*100
constexpr size_t OFF_H1P     = OFF_VP + 16384 * 100;  // 16384*100

// ---------------- setup: prevec (blk 0) + destpre (1..64) + wfused (65..192) ----------------
__global__ void __launch_bounds__(256) k_setup(
    const int* destinations, const float* emb, const float* Wo,
    const float* dist_W, const float* dist_b, const float* dir_W, const float* dir_b,
    const float* tt_W, const float* tt_b, const float* ob_W1, const float* ob_b1,
    const float* ob_W2, const float* ob_b2, const float* om_W1, const float* om_b1,
    float* ws, float* out) {
    __shared__ float sh[EE];
    int blk = blockIdx.x;
    int j = threadIdx.x;
    if (blk == 0) {
        if (j < 4) ws[OFF_STATS + j] = 0.f;
        if (j == 0) out[0] = 0.f;
        if (j < HID) {
            float cd = 0.f, cx = 0.f, cy = 0.f, bs = om_b1[j];
            for (int f = 0; f < 50; f++) {
                float w1d = om_W1[(128 + f) * HID + j];
                float w1r = om_W1[(178 + f) * HID + j];
                cd += dist_W[f] * w1d;
                bs += dist_b[f] * w1d + dir_b[f] * w1r;
                cx += dir_W[f] * w1r;
                cy += dir_W[50 + f] * w1r;
            }
            ws[OFF_CDIST + j] = cd; ws[OFF_CDIRX + j] = cx;
            ws[OFF_CDIRY + j] = cy; ws[OFF_BASE + j] = bs;
        }
        if (j >= 128 && j < 153) {
            int jj = j - 128;
            float v = 0.f, c = ob_b1[jj];
            for (int i = 0; i < 50; i++) {
                v += tt_W[i] * ob_W1[i * 25 + jj];
                c += tt_b[i] * ob_W1[i * 25 + jj];
            }
            ws[OFF_V25 + jj] = v; ws[OFF_C25 + jj] = c;
        }
        if (j == 200) {
            float z = ob_b2[0];
            for (int i = 0; i < 25; i++) z += fmaxf(ob_b1[i], 0.f) * ob_W2[i];
            ws[OFF_OBZ] = z;
        }
    } else if (blk <= 64) {
        int b = blk - 1;
        if (j < EE) sh[j] = emb[(size_t)destinations[b] * EE + j];
        __syncthreads();
        if (j < HID) {
            float acc = 0.f;
            for (int i = 0; i < EE; i++) acc += sh[i] * om_W1[(228 + i) * HID + j];
            ws[OFF_DESTPRE + b * HID + j] = acc;
        }
    } else {
        int i = blk - 65;
        if (j < EE) sh[j] = Wo[i * EE + j];
        __syncthreads();
        if (j < HID) {
            float acc = 0.f;
            for (int jj = 0; jj < EE; jj++) acc += sh[jj] * om_W1[jj * HID + j];
            ws[OFF_WF + i * HID + j] = acc;
        }
    }
}

// ---------------- mid: QKV' GEMM (blocks 0..511) + whitening stats (512..767) ----------------
__global__ void __launch_bounds__(256) k_mid(
    const int* xs, const int* lengths, const int* adj, const int* seg,
    const int* stime, const float* tds, const float* emb,
    const float* Wq, const float* Wk, const float* Wv, float* ws) {
    __shared__ float smem[2 * 128 * 36 + 32];
    int blk = blockIdx.x;
    int tid = threadIdx.x;
    if (blk < 512) {
        float (*XT)[36]  = (float(*)[36])smem;
        float (*T1T)[36] = (float(*)[36])(smem + 128 * 36);
        int* vids = (int*)(smem + 2 * 128 * 36);
        int r0 = blk * 32;
        if (tid < 32) vids[tid] = xs[r0 + tid];
        __syncthreads();
        for (int c = 0; c < 16; c++) {
            int idx = c * 256 + tid;
            int r = idx >> 7, i = idx & 127;
            XT[i][r] = emb[(size_t)vids[r] * EE + i];
        }
        __syncthreads();
        int cg = tid & 31, rg = tid >> 5;
        const float* Wmats[2] = {Wq, Wk};
        float* Omats[2] = {ws + OFF_Q, ws + OFF_K};
        for (int mtx = 0; mtx < 2; mtx++) {
            const float* W = Wmats[mtx];
            float acc[4][4];
            #pragma unroll
            for (int a = 0; a < 4; a++)
                #pragma unroll
                for (int bb = 0; bb < 4; bb++) acc[a][bb] = 0.f;
            #pragma unroll 4
            for (int i = 0; i < EE; i++) {
                float4 av = *(const float4*)&XT[i][rg << 2];
                float4 wv = *(const float4*)&W[i * EE + (cg << 2)];
                acc[0][0] += av.x * wv.x; acc[0][1] += av.x * wv.y; acc[0][2] += av.x * wv.z; acc[0][3] += av.x * wv.w;
                acc[1][0] += av.y * wv.x; acc[1][1] += av.y * wv.y; acc[1][2] += av.y * wv.z; acc[1][3] += av.y * wv.w;
                acc[2][0] += av.z * wv.x; acc[2][1] += av.z * wv.y; acc[2][2] += av.z * wv.z; acc[2][3] += av.z * wv.w;
                acc[3][0] += av.w * wv.x; acc[3][1] += av.w * wv.y; acc[3][2] += av.w * wv.z; acc[3][3] += av.w * wv.w;
            }
            float* O = Omats[mtx];
            #pragma unroll
            for (int jj = 0; jj < 4; jj++)
                *(float4*)&O[(size_t)(r0 + (rg << 2) + jj) * EE + (cg << 2)] =
                    make_float4(acc[jj][0], acc[jj][1], acc[jj][2], acc[jj][3]);
        }
        // T1 = X @ Wv, transposed into LDS
        {
            float acc[4][4];
            #pragma unroll
            for (int a = 0; a < 4; a++)
                #pragma unroll
                for (int bb = 0; bb < 4; bb++) acc[a][bb] = 0.f;
            #pragma unroll 4
            for (int i = 0; i < EE; i++) {
                float4 av = *(const float4*)&XT[i][rg << 2];
                float4 wv = *(const float4*)&Wv[i * EE + (cg << 2)];
                acc[0][0] += av.x * wv.x; acc[0][1] += av.x * wv.y; acc[0][2] += av.x * wv.z; acc[0][3] += av.x * wv.w;
                acc[1][0] += av.y * wv.x; acc[1][1] += av.y * wv.y; acc[1][2] += av.y * wv.z; acc[1][3] += av.y * wv.w;
                acc[2][0] += av.z * wv.x; acc[2][1] += av.z * wv.y; acc[2][2] += av.z * wv.z; acc[2][3] += av.z * wv.w;
                acc[3][0] += av.w * wv.x; acc[3][1] += av.w * wv.y; acc[3][2] += av.w * wv.z; acc[3][3] += av.w * wv.w;
            }
            #pragma unroll
            for (int jj = 0; jj < 4; jj++)
                #pragma unroll
                for (int ii = 0; ii < 4; ii++)
                    T1T[(cg << 2) + ii][(rg << 2) + jj] = acc[jj][ii];
        }
        __syncthreads();
        if (cg < 25) {
            const float* WF = ws + OFF_WF;
            float acc[4][4];
            #pragma unroll
            for (int a = 0; a < 4; a++)
                #pragma unroll
                for (int bb = 0; bb < 4; bb++) acc[a][bb] = 0.f;
            #pragma unroll 4
            for (int i = 0; i < EE; i++) {
                float4 av = *(const float4*)&T1T[i][rg << 2];
                float4 wv = *(const float4*)&WF[i * HID + (cg << 2)];
                acc[0][0] += av.x * wv.x; acc[0][1] += av.x * wv.y; acc[0][2] += av.x * wv.z; acc[0][3] += av.x * wv.w;
                acc[1][0] += av.y * wv.x; acc[1][1] += av.y * wv.y; acc[1][2] += av.y * wv.z; acc[1][3] += av.y * wv.w;
                acc[2][0] += av.z * wv.x; acc[2][1] += av.z * wv.y; acc[2][2] += av.z * wv.z; acc[2][3] += av.z * wv.w;
                acc[3][0] += av.w * wv.x; acc[3][1] += av.w * wv.y; acc[3][2] += av.w * wv.z; acc[3][3] += av.w * wv.w;
            }
            float* VP = ws + OFF_VP;
            #pragma unroll
            for (int jj = 0; jj < 4; jj++)
                *(float4*)&VP[(size_t)(r0 + (rg << 2) + jj) * HID + (cg << 2)] =
                    make_float4(acc[jj][0], acc[jj][1], acc[jj][2], acc[jj][3]);
        }
    } else {
        // ---- stats ----
        float* rs = smem; float* rq = smem + 256; float* rc = smem + 512;
        int st = *stime;
        float lsum = 0.f, lsq = 0.f, lcnt = 0.f;
        int total = BB * TT * DEG;
        for (int idx = (blk - 512) * 256 + tid; idx < total; idx += 256 * 256) {
            int d = idx & 7;
            int bt = idx >> 3;
            int t = bt & 255;
            int b = bt >> 8;
            int len = lengths[b];
            if (t >= len - 1) continue;
            int v = xs[bt];
            int sg = seg[v * DEG + d];
            float tt = tds[(size_t)sg * NBUCKET + st];
            ws[OFF_TT + idx] = tt;
            int a = adj[v * DEG + d];
            if (a != 0) { lsum += tt; lsq += tt * tt; lcnt += 1.f; }
        }
        rs[tid] = lsum; rq[tid] = lsq; rc[tid] = lcnt;
        __syncthreads();
        for (int s = 128; s > 0; s >>= 1) {
            if (tid < s) { rs[tid] += rs[tid + s]; rq[tid] += rq[tid + s]; rc[tid] += rc[tid + s]; }
            __syncthreads();
        }
        if (tid == 0) {
            atomicAdd(&ws[OFF_STATS + 0], rs[0]);
            atomicAdd(&ws[OFF_STATS + 1], rq[0]);
            atomicAdd(&ws[OFF_STATS + 2], rc[0]);
        }
    }
}

// ---------------- tiled attention: 16 queries/block + fused H1P epilogue ----------------
__global__ void __launch_bounds__(256) k_attn(const int* lengths, float* ws) {
    int b = blockIdx.x >> 4;
    int tile = blockIdx.x & 15;
    int t0 = tile << 4;
    int len = lengths[b];
    if (t0 >= len - 1) return;
    int nk = t0 + 16;           // keys 0..nk-1 staged
    int nm = nk >> 4;           // 16-key groups
    __shared__ float Qs[16][132];
    __shared__ float S[16][260];
    __shared__ float KV[32 * 136];   // union: K [32][136] / V [32][104]
    int tid = threadIdx.x;
    const float* Q  = ws + OFF_Q;
    const float* K  = ws + OFF_K;
    const float* VP = ws + OFF_VP;
    {
        const float* Qg = Q + ((size_t)(b * TT + t0)) * EE;
        for (int idx = tid; idx < 512; idx += 256) {
            int r = idx >> 5, c4 = (idx & 31) << 2;
            *(float4*)&Qs[r][c4] = *(const float4*)&Qg[r * EE + c4];
        }
    }
    int q = tid >> 4, li = tid & 15;
    int tq = t0 + q;
    float sreg[16];
    #pragma unroll
    for (int m = 0; m < 16; m++) sreg[m] = -1e30f;
    float (*Ks)[136] = (float(*)[136])KV;
    int ktend = ((nk + 31) >> 5) << 5;
    for (int kt = 0; kt < ktend; kt += 32) {
        __syncthreads();
        const float* Kg = K + ((size_t)(b * TT + kt)) * EE;
        for (int idx = tid; idx < 1024; idx += 256) {
            int r = idx >> 5, c4 = (idx & 31) << 2;
            *(float4*)&Ks[r][c4] = *(const float4*)&Kg[r * EE + c4];
        }
        __syncthreads();
        int k0 = kt + li, k1 = kt + li + 16;
        float s0 = 0.f, s1 = 0.f;
        const float4* q4  = (const float4*)Qs[q];
        const float4* k4a = (const float4*)Ks[li];
        const float4* k4b = (const float4*)Ks[li + 16];
        #pragma unroll 8
        for (int i = 0; i < 32; i++) {
            float4 a = q4[i];
            float4 x = k4a[i];
            float4 y = k4b[i];
            s0 += a.x * x.x + a.y * x.y + a.z * x.z + a.w * x.w;
            s1 += a.x * y.x + a.y * y.y + a.z * y.z + a.w * y.w;
        }
        int m0 = kt >> 4;
        if (k0 < nk && k0 <= tq) sreg[m0]     = s0 * 0.08838834764831845f;
        if (k1 < nk && k1 <= tq) sreg[m0 + 1] = s1 * 0.08838834764831845f;
    }
    // softmax across this query's 16 lanes
    float mx = -1e30f;
    for (int m = 0; m < nm; m++) mx = fmaxf(mx, sreg[m]);
    #pragma unroll
    for (int o = 1; o < 16; o <<= 1) mx = fmaxf(mx, __shfl_xor(mx, o, 16));
    float lsum = 0.f;
    for (int m = 0; m < nm; m++) { float p = __expf(sreg[m] - mx); sreg[m] = p; lsum += p; }
    #pragma unroll
    for (int o = 1; o < 16; o <<= 1) lsum += __shfl_xor(lsum, o, 16);
    float inv = 1.f / lsum;
    for (int m = 0; m < nm; m++) S[q][li + (m << 4)] = sreg[m];
    // PV
    float acc[7];
    #pragma unroll
    for (int j = 0; j < 7; j++) acc[j] = 0.f;
    float (*Vs)[104] = (float(*)[104])KV;
    for (int vt = 0; vt < nk; vt += 32) {
        __syncthreads();
        const float* Vg = VP + ((size_t)(b * TT + vt)) * HID;
        for (int idx = tid; idx < 800; idx += 256) {
            int r = idx / 25, c4 = (idx - r * 25) << 2;
            *(float4*)&Vs[r][c4] = *(const float4*)&Vg[r * HID + c4];
        }
        __syncthreads();
        int kmax = nk - vt; if (kmax > 32) kmax = 32;
        for (int k = 0; k < kmax; k++) {
            float p = S[q][vt + k];
            #pragma unroll
            for (int j = 0; j < 7; j++) {
                int c = li + (j << 4);
                if (c < HID) acc[j] += p * Vs[k][c];
            }
        }
    }
    if (tq < len - 1) {
        float* H = ws + OFF_H1P + (size_t)(b * TT + tq) * HID;
        const float* BASEv = ws + OFF_BASE;
        const float* DP = ws + OFF_DESTPRE + b * HID;
        #pragma unroll
        for (int j = 0; j < 7; j++) {
            int c = li + (j << 4);
            if (c < HID) H[c] = acc[j] * inv + BASEv[c] + DP[c];
        }
    }
}

// ---------------- final: features + h2 GEMM + CE; 16 (b,t) pairs/block ----------------
__global__ void __launch_bounds__(256) k_final(
    const int* xs, const int* lengths, const int* xs_actions, const int* destinations,
    const int* adj, const float* locations,
    const float* om_W2, const float* om_b2, const float* om_W3, const float* om_b3,
    const float* ob_W2, const float* ob_b2,
    const float* ws, float* out)
{
    __shared__ float W2T[H2][104];
    __shared__ float h1s[4][DEG][104];
    __shared__ float nlls[4];
    int tid = threadIdx.x;
    for (int idx = tid; idx < HID * H2; idx += 256) {
        int mm = idx / H2, n = idx - mm * H2;
        W2T[n][mm] = om_W2[idx];
    }
    if (tid < 4) nlls[tid] = 0.f;
    int w = tid >> 6, lane = tid & 63;
    int r = lane >> 3, li = lane & 7;
    float sum = ws[OFF_STATS], sq = ws[OFF_STATS + 1], cnt = ws[OFF_STATS + 2];
    float mean = sum / cnt;
    float var = (sq - cnt * mean * mean) / (cnt - 1.f);
    float sdinv = 1.f / (sqrtf(var) + 1e-6f);
    __syncthreads();
    for (int it = 0; it < 4; it++) {
        int pi = blockIdx.x * 16 + it * 4 + w;
        int b = pi / (TT - 1), t = pi - b * (TT - 1);
        int len = lengths[b];
        bool valid = (t < len - 1);
        int bt = b * TT + t;
        if (valid) {
            float distv = 0.f, uxv = 0.f, uyv = 0.f, obv = 0.f;
            if (lane < 8) {
                int v = xs[bt];
                int a = adj[v * DEG + lane];
                float nbx = locations[2 * a], nby = locations[2 * a + 1];
                int dst = destinations[b];
                float dxl = locations[2 * dst], dyl = locations[2 * dst + 1];
                float cxl = locations[2 * v], cyl = locations[2 * v + 1];
                distv = (fabsf(nbx - dxl) + fabsf(nby - dyl)) * 100.f;
                float vx = nbx - cxl, vy = nby - cyl;
                float nrm = sqrtf(vx * vx + vy * vy) + 1e-8f;
                uxv = vx / nrm; uyv = vy / nrm;
                float ttn = (ws[OFF_TT + (size_t)bt * 8 + lane] - mean) * sdinv;
                float obp = 0.f;
                for (int j = 0; j < 25; j++)
                    obp += fmaxf(ttn * ws[OFF_V25 + j] + ws[OFF_C25 + j], 0.f) * ob_W2[j];
                obv = (a != 0) ? (obp + ob_b2[0]) : ws[OFF_OBZ];
            }
            distv = __shfl(distv, r, 64);
            uxv   = __shfl(uxv, r, 64);
            uyv   = __shfl(uyv, r, 64);
            obv   = __shfl(obv, r, 64);
            const float* H = ws + OFF_H1P + (size_t)bt * HID;
            for (int mm = li; mm < HID; mm += 8) {
                float pre = H[mm] + distv * ws[OFF_CDIST + mm]
                          + uxv * ws[OFF_CDIRX + mm] + uyv * ws[OFF_CDIRY + mm];
                h1s[w][r][mm] = fmaxf(pre, 0.f);
            }
            float acc[7] = {0.f, 0.f, 0.f, 0.f, 0.f, 0.f, 0.f};
            const float4* hv4 = (const float4*)h1s[w][r];
            for (int ks = 0; ks < 25; ks++) {
                float4 h = hv4[ks];
                #pragma unroll
                for (int j = 0; j < 7; j++) {
                    int n = li + 8 * j;
                    if (n < H2) {
                        float4 wv = *(const float4*)&W2T[n][ks << 2];
                        acc[j] += h.x * wv.x + h.y * wv.y + h.z * wv.z + h.w * wv.w;
                    }
                }
            }
            float part = 0.f;
            #pragma unroll
            for (int j = 0; j < 7; j++) {
                int n = li + 8 * j;
                if (n < H2) part += fmaxf(acc[j] + om_b2[n], 0.f) * om_W3[n];
            }
            part += __shfl_xor(part, 1, 8);
            part += __shfl_xor(part, 2, 8);
            part += __shfl_xor(part, 4, 8);
            float logit = part + om_b3[0] + obv;
            float lgv[8];
            float mx = -1e30f;
            #pragma unroll
            for (int d = 0; d < 8; d++) {
                lgv[d] = __shfl(logit, d << 3, 64);
                mx = fmaxf(mx, lgv[d]);
            }
            if (lane == 0) {
                int act = xs_actions[b * (TT - 1) + t];
                float se = 0.f, sel = 0.f;
                #pragma unroll
                for (int d = 0; d < 8; d++) {
                    se += __expf(lgv[d] - mx);
                    if (d == act) sel = lgv[d];
                }
                float nll = mx + __logf(se) - sel;
                nlls[w] += nll / (float)(len - 1);
            }
        }
    }
    __syncthreads();
    if (tid == 0) {
        atomicAdd(out, nlls[0] + nlls[1] + nlls[2] + nlls[3]);
    }
}

extern "C" void kernel_launch(void* const* d_in, const int* in_sizes, int n_in,
                              void* d_out, int out_size, void* d_ws, size_t ws_size,
                              hipStream_t stream) {
    const int* xs_padded    = (const int*)d_in[0];
    const int* lengths      = (const int*)d_in[1];
    const int* xs_actions   = (const int*)d_in[2];
    const int* destinations = (const int*)d_in[3];
    const int* adj_list     = (const int*)d_in[4];
    const int* seg_ids      = (const int*)d_in[5];
    const int* start_time   = (const int*)d_in[6];
    const float* locations  = (const float*)d_in[7];
    const float* tds        = (const float*)d_in[8];
    const float* emb        = (const float*)d_in[9];
    const float* Wq         = (const float*)d_in[10];
    const float* Wk         = (const float*)d_in[11];
    const float* Wv         = (const float*)d_in[12];
    const float* Wo         = (const float*)d_in[13];
    const float* dist_W     = (const float*)d_in[14];
    const float* dist_b     = (const float*)d_in[15];
    const float* dir_W      = (const float*)d_in[16];
    const float* dir_b      = (const float*)d_in[17];
    const float* tt_W       = (const float*)d_in[18];
    const float* tt_b       = (const float*)d_in[19];
    const float* ob_W1      = (const float*)d_in[20];
    const float* ob_b1      = (const float*)d_in[21];
    const float* ob_W2      = (const float*)d_in[22];
    const float* ob_b2      = (const float*)d_in[23];
    const float* om_W1      = (const float*)d_in[24];
    const float* om_b1      = (const float*)d_in[25];
    const float* om_W2      = (const float*)d_in[26];
    const float* om_b2      = (const float*)d_in[27];
    const float* om_W3      = (const float*)d_in[28];
    const float* om_b3      = (const float*)d_in[29];
    float* ws  = (float*)d_ws;
    float* out = (float*)d_out;

    k_setup<<<193, 256, 0, stream>>>(destinations, emb, Wo, dist_W, dist_b,
                                     dir_W, dir_b, tt_W, tt_b, ob_W1, ob_b1,
                                     ob_W2, ob_b2, om_W1, om_b1, ws, out);
    k_mid<<<768, 256, 0, stream>>>(xs_padded, lengths, adj_list, seg_ids,
                                   start_time, tds, emb, Wq, Wk, Wv, ws);
    k_attn<<<BB * 16, 256, 0, stream>>>(lengths, ws);
    k_final<<<1020, 256, 0, stream>>>(
        xs_padded, lengths, xs_actions, destinations, adj_list, locations,
        om_W2, om_b2, om_W3, om_b3, ob_W2, ob_b2, ws, out);
}

// Round 4
// 471.464 us; speedup vs baseline: 1.3104x; 1.0265x over previous
//
#include <hip/hip_runtime.h>
#include <math.h>

#define BB 64
#define TT 256
#define DEG 8
#define EE 128
#define NBUCKET 288
#define HID 100
#define H2 50

// ---------------- workspace layout (floats) ----------------
constexpr size_t OFF_STATS   = 0;        // 4: sum, sumsq, cnt, pad
constexpr size_t OFF_CDIST   = 4;        // 100
constexpr size_t OFF_CDIRX   = 104;      // 100
constexpr size_t OFF_CDIRY   = 204;      // 100
constexpr size_t OFF_BASE    = 304;      // 100
constexpr size_t OFF_V25     = 404;      // 25
constexpr size_t OFF_C25     = 429;      // 25
constexpr size_t OFF_OBZ     = 454;      // 1
constexpr size_t OFF_DESTPRE = 456;      // 64*100
constexpr size_t OFF_WF      = 6856;     // 128*100 (Wo @ om_W1[0:128])
constexpr size_t OFF_TT      = 32456;    // 16384*8 travel times
constexpr size_t OFF_Q       = 163528;   // 16384*128
constexpr size_t OFF_K       = OFF_Q + 16384 * 128;
constexpr size_t OFF_VP      = OFF_K + 16384 * 128;   // 16384*100

// ---------------- setup: prevec (blk 0) + destpre (1..64) + wfused (65..192) ----------------
__global__ void __launch_bounds__(256) k_setup(
    const int* destinations, const float* emb, const float* Wo,
    const float* dist_W, const float* dist_b, const float* dir_W, const float* dir_b,
    const float* tt_W, const float* tt_b, const float* ob_W1, const float* ob_b1,
    const float* ob_W2, const float* ob_b2, const float* om_W1, const float* om_b1,
    float* ws, float* out) {
    __shared__ float sh[EE];
    int blk = blockIdx.x;
    int j = threadIdx.x;
    if (blk == 0) {
        if (j < 4) ws[OFF_STATS + j] = 0.f;
        if (j == 0) out[0] = 0.f;
        if (j < HID) {
            float cd = 0.f, cx = 0.f, cy = 0.f, bs = om_b1[j];
            for (int f = 0; f < 50; f++) {
                float w1d = om_W1[(128 + f) * HID + j];
                float w1r = om_W1[(178 + f) * HID + j];
                cd += dist_W[f] * w1d;
                bs += dist_b[f] * w1d + dir_b[f] * w1r;
                cx += dir_W[f] * w1r;
                cy += dir_W[50 + f] * w1r;
            }
            ws[OFF_CDIST + j] = cd; ws[OFF_CDIRX + j] = cx;
            ws[OFF_CDIRY + j] = cy; ws[OFF_BASE + j] = bs;
        }
        if (j >= 128 && j < 153) {
            int jj = j - 128;
            float v = 0.f, c = ob_b1[jj];
            for (int i = 0; i < 50; i++) {
                v += tt_W[i] * ob_W1[i * 25 + jj];
                c += tt_b[i] * ob_W1[i * 25 + jj];
            }
            ws[OFF_V25 + jj] = v; ws[OFF_C25 + jj] = c;
        }
        if (j == 200) {
            float z = ob_b2[0];
            for (int i = 0; i < 25; i++) z += fmaxf(ob_b1[i], 0.f) * ob_W2[i];
            ws[OFF_OBZ] = z;
        }
    } else if (blk <= 64) {
        int b = blk - 1;
        if (j < EE) sh[j] = emb[(size_t)destinations[b] * EE + j];
        __syncthreads();
        if (j < HID) {
            float acc = 0.f;
            for (int i = 0; i < EE; i++) acc += sh[i] * om_W1[(228 + i) * HID + j];
            ws[OFF_DESTPRE + b * HID + j] = acc;
        }
    } else {
        int i = blk - 65;
        if (j < EE) sh[j] = Wo[i * EE + j];
        __syncthreads();
        if (j < HID) {
            float acc = 0.f;
            for (int jj = 0; jj < EE; jj++) acc += sh[jj] * om_W1[jj * HID + j];
            ws[OFF_WF + i * HID + j] = acc;
        }
    }
}

// ---------------- mid: QKV' GEMM (blocks 0..511) + whitening stats (512..767) ----------------
__global__ void __launch_bounds__(256) k_mid(
    const int* xs, const int* lengths, const int* adj, const int* seg,
    const int* stime, const float* tds, const float* emb,
    const float* Wq, const float* Wk, const float* Wv, float* ws) {
    __shared__ float smem[2 * 128 * 36 + 32];
    int blk = blockIdx.x;
    int tid = threadIdx.x;
    if (blk < 512) {
        float (*XT)[36]  = (float(*)[36])smem;
        float (*T1T)[36] = (float(*)[36])(smem + 128 * 36);
        int* vids = (int*)(smem + 2 * 128 * 36);
        int r0 = blk * 32;
        if (tid < 32) vids[tid] = xs[r0 + tid];
        __syncthreads();
        for (int c = 0; c < 16; c++) {
            int idx = c * 256 + tid;
            int r = idx >> 7, i = idx & 127;
            XT[i][r] = emb[(size_t)vids[r] * EE + i];
        }
        __syncthreads();
        int cg = tid & 31, rg = tid >> 5;
        const float* Wmats[2] = {Wq, Wk};
        float* Omats[2] = {ws + OFF_Q, ws + OFF_K};
        for (int mtx = 0; mtx < 2; mtx++) {
            const float* W = Wmats[mtx];
            float acc[4][4];
            #pragma unroll
            for (int a = 0; a < 4; a++)
                #pragma unroll
                for (int bb = 0; bb < 4; bb++) acc[a][bb] = 0.f;
            #pragma unroll 4
            for (int i = 0; i < EE; i++) {
                float4 av = *(const float4*)&XT[i][rg << 2];
                float4 wv = *(const float4*)&W[i * EE + (cg << 2)];
                acc[0][0] += av.x * wv.x; acc[0][1] += av.x * wv.y; acc[0][2] += av.x * wv.z; acc[0][3] += av.x * wv.w;
                acc[1][0] += av.y * wv.x; acc[1][1] += av.y * wv.y; acc[1][2] += av.y * wv.z; acc[1][3] += av.y * wv.w;
                acc[2][0] += av.z * wv.x; acc[2][1] += av.z * wv.y; acc[2][2] += av.z * wv.z; acc[2][3] += av.z * wv.w;
                acc[3][0] += av.w * wv.x; acc[3][1] += av.w * wv.y; acc[3][2] += av.w * wv.z; acc[3][3] += av.w * wv.w;
            }
            float* O = Omats[mtx];
            #pragma unroll
            for (int jj = 0; jj < 4; jj++)
                *(float4*)&O[(size_t)(r0 + (rg << 2) + jj) * EE + (cg << 2)] =
                    make_float4(acc[jj][0], acc[jj][1], acc[jj][2], acc[jj][3]);
        }
        // T1 = X @ Wv, transposed into LDS
        {
            float acc[4][4];
            #pragma unroll
            for (int a = 0; a < 4; a++)
                #pragma unroll
                for (int bb = 0; bb < 4; bb++) acc[a][bb] = 0.f;
            #pragma unroll 4
            for (int i = 0; i < EE; i++) {
                float4 av = *(const float4*)&XT[i][rg << 2];
                float4 wv = *(const float4*)&Wv[i * EE + (cg << 2)];
                acc[0][0] += av.x * wv.x; acc[0][1] += av.x * wv.y; acc[0][2] += av.x * wv.z; acc[0][3] += av.x * wv.w;
                acc[1][0] += av.y * wv.x; acc[1][1] += av.y * wv.y; acc[1][2] += av.y * wv.z; acc[1][3] += av.y * wv.w;
                acc[2][0] += av.z * wv.x; acc[2][1] += av.z * wv.y; acc[2][2] += av.z * wv.z; acc[2][3] += av.z * wv.w;
                acc[3][0] += av.w * wv.x; acc[3][1] += av.w * wv.y; acc[3][2] += av.w * wv.z; acc[3][3] += av.w * wv.w;
            }
            #pragma unroll
            for (int jj = 0; jj < 4; jj++)
                #pragma unroll
                for (int ii = 0; ii < 4; ii++)
                    T1T[(cg << 2) + ii][(rg << 2) + jj] = acc[jj][ii];
        }
        __syncthreads();
        if (cg < 25) {
            const float* WF = ws + OFF_WF;
            float acc[4][4];
            #pragma unroll
            for (int a = 0; a < 4; a++)
                #pragma unroll
                for (int bb = 0; bb < 4; bb++) acc[a][bb] = 0.f;
            #pragma unroll 4
            for (int i = 0; i < EE; i++) {
                float4 av = *(const float4*)&T1T[i][rg << 2];
                float4 wv = *(const float4*)&WF[i * HID + (cg << 2)];
                acc[0][0] += av.x * wv.x; acc[0][1] += av.x * wv.y; acc[0][2] += av.x * wv.z; acc[0][3] += av.x * wv.w;
                acc[1][0] += av.y * wv.x; acc[1][1] += av.y * wv.y; acc[1][2] += av.y * wv.z; acc[1][3] += av.y * wv.w;
                acc[2][0] += av.z * wv.x; acc[2][1] += av.z * wv.y; acc[2][2] += av.z * wv.z; acc[2][3] += av.z * wv.w;
                acc[3][0] += av.w * wv.x; acc[3][1] += av.w * wv.y; acc[3][2] += av.w * wv.z; acc[3][3] += av.w * wv.w;
            }
            float* VP = ws + OFF_VP;
            #pragma unroll
            for (int jj = 0; jj < 4; jj++)
                *(float4*)&VP[(size_t)(r0 + (rg << 2) + jj) * HID + (cg << 2)] =
                    make_float4(acc[jj][0], acc[jj][1], acc[jj][2], acc[jj][3]);
        }
    } else {
        // ---- stats ----
        float* rs = smem; float* rq = smem + 256; float* rc = smem + 512;
        int st = *stime;
        float lsum = 0.f, lsq = 0.f, lcnt = 0.f;
        int total = BB * TT * DEG;
        for (int idx = (blk - 512) * 256 + tid; idx < total; idx += 256 * 256) {
            int d = idx & 7;
            int bt = idx >> 3;
            int t = bt & 255;
            int b = bt >> 8;
            int len = lengths[b];
            if (t >= len - 1) continue;
            int v = xs[bt];
            int sg = seg[v * DEG + d];
            float tt = tds[(size_t)sg * NBUCKET + st];
            ws[OFF_TT + idx] = tt;
            int a = adj[v * DEG + d];
            if (a != 0) { lsum += tt; lsq += tt * tt; lcnt += 1.f; }
        }
        rs[tid] = lsum; rq[tid] = lsq; rc[tid] = lcnt;
        __syncthreads();
        for (int s = 128; s > 0; s >>= 1) {
            if (tid < s) { rs[tid] += rs[tid + s]; rq[tid] += rq[tid + s]; rc[tid] += rc[tid + s]; }
            __syncthreads();
        }
        if (tid == 0) {
            atomicAdd(&ws[OFF_STATS + 0], rs[0]);
            atomicAdd(&ws[OFF_STATS + 1], rq[0]);
            atomicAdd(&ws[OFF_STATS + 2], rc[0]);
        }
    }
}

// ---------------- fused attention + neighbor-MLP + CE: 16 queries/block ----------------
// LDS carve (floats): S[16][260]=4160 @0 | Qs[16][132]=2112 @4160 | KV=4352 @6272
// phase B: W2s[100][64]=6400 @4160 | h1T[100][68]=6800 @10560 |
//          distR/uxR/uyR/obR[64] @17360.. | lgS[64] @17616 | nllS[16] @17680
__global__ void __launch_bounds__(256) k_attnfinal(
    const int* lengths, const int* xs, const int* xs_actions,
    const int* destinations, const int* adj, const float* locations,
    const float* om_W2, const float* om_b2, const float* om_W3, const float* om_b3,
    const float* ob_W2, const float* ob_b2,
    float* ws, float* out) {
    int b = blockIdx.x >> 4;
    int tile = blockIdx.x & 15;
    int t0 = tile << 4;
    int len = lengths[b];
    if (t0 >= len - 1) return;
    int nqv = len - 1 - t0; if (nqv > 16) nqv = 16;
    int nk = t0 + 16;
    int nm = nk >> 4;
    __shared__ float smem[17696];
    float (*S)[260]  = (float(*)[260])smem;
    float (*Qs)[132] = (float(*)[132])(smem + 4160);
    float* KV = smem + 6272;
    int tid = threadIdx.x;
    if (tid < 16) smem[17680 + tid] = 0.f;   // nllS
    const float* Q  = ws + OFF_Q;
    const float* K  = ws + OFF_K;
    const float* VP = ws + OFF_VP;
    {
        const float* Qg = Q + ((size_t)(b * TT + t0)) * EE;
        for (int idx = tid; idx < 512; idx += 256) {
            int r = idx >> 5, c4 = (idx & 31) << 2;
            *(float4*)&Qs[r][c4] = *(const float4*)&Qg[r * EE + c4];
        }
    }
    int q = tid >> 4, li = tid & 15;
    int tq = t0 + q;
    float sreg[16];
    #pragma unroll
    for (int m = 0; m < 16; m++) sreg[m] = -1e30f;
    float (*Ks)[136] = (float(*)[136])KV;
    int ktend = ((nk + 31) >> 5) << 5;
    for (int kt = 0; kt < ktend; kt += 32) {
        __syncthreads();
        const float* Kg = K + ((size_t)(b * TT + kt)) * EE;
        for (int idx = tid; idx < 1024; idx += 256) {
            int r = idx >> 5, c4 = (idx & 31) << 2;
            *(float4*)&Ks[r][c4] = *(const float4*)&Kg[r * EE + c4];
        }
        __syncthreads();
        int k0 = kt + li, k1 = kt + li + 16;
        float s0 = 0.f, s1 = 0.f;
        const float4* q4  = (const float4*)Qs[q];
        const float4* k4a = (const float4*)Ks[li];
        const float4* k4b = (const float4*)Ks[li + 16];
        #pragma unroll 8
        for (int i = 0; i < 32; i++) {
            float4 a = q4[i];
            float4 x = k4a[i];
            float4 y = k4b[i];
            s0 += a.x * x.x + a.y * x.y + a.z * x.z + a.w * x.w;
            s1 += a.x * y.x + a.y * y.y + a.z * y.z + a.w * y.w;
        }
        int m0 = kt >> 4;
        if (k0 < nk && k0 <= tq) sreg[m0]     = s0 * 0.08838834764831845f;
        if (k1 < nk && k1 <= tq) sreg[m0 + 1] = s1 * 0.08838834764831845f;
    }
    float mx = -1e30f;
    for (int m = 0; m < nm; m++) mx = fmaxf(mx, sreg[m]);
    #pragma unroll
    for (int o = 1; o < 16; o <<= 1) mx = fmaxf(mx, __shfl_xor(mx, o, 16));
    float lsum = 0.f;
    for (int m = 0; m < nm; m++) { float p = __expf(sreg[m] - mx); sreg[m] = p; lsum += p; }
    #pragma unroll
    for (int o = 1; o < 16; o <<= 1) lsum += __shfl_xor(lsum, o, 16);
    float inv = 1.f / lsum;
    for (int m = 0; m < nm; m++) S[q][li + (m << 4)] = sreg[m];
    float acc[7];
    #pragma unroll
    for (int j = 0; j < 7; j++) acc[j] = 0.f;
    float (*Vs)[104] = (float(*)[104])KV;
    for (int vt = 0; vt < nk; vt += 32) {
        __syncthreads();
        const float* Vg = VP + ((size_t)(b * TT + vt)) * HID;
        for (int idx = tid; idx < 800; idx += 256) {
            int r = idx / 25, c4 = (idx - r * 25) << 2;
            *(float4*)&Vs[r][c4] = *(const float4*)&Vg[r * HID + c4];
        }
        __syncthreads();
        int kmax = nk - vt; if (kmax > 32) kmax = 32;
        for (int k = 0; k < kmax; k++) {
            float p = S[q][vt + k];
            #pragma unroll
            for (int j = 0; j < 7; j++) {
                int c = li + (j << 4);
                if (c < HID) acc[j] += p * Vs[k][c];
            }
        }
    }
    __syncthreads();   // PV complete; S scores dead, Qs/KV dead
    // H1P into S[q][0..99]; stage W2s
    {
        const float* BASEv = ws + OFF_BASE;
        const float* DP = ws + OFF_DESTPRE + b * HID;
        #pragma unroll
        for (int j = 0; j < 7; j++) {
            int c = li + (j << 4);
            if (c < HID) S[q][c] = acc[j] * inv + BASEv[c] + DP[c];
        }
    }
    float (*W2s)[64] = (float(*)[64])(smem + 4160);
    for (int idx = tid; idx < 6400; idx += 256) {
        int mm = idx >> 6, n = idx & 63;
        W2s[mm][n] = (n < H2) ? om_W2[mm * H2 + n] : 0.f;
    }
    float smean, sdinv;
    {
        float sum = ws[OFF_STATS], sq = ws[OFF_STATS + 1], cnt = ws[OFF_STATS + 2];
        smean = sum / cnt;
        float var = (sq - cnt * smean * smean) / (cnt - 1.f);
        sdinv = 1.f / (sqrtf(var) + 1e-6f);
    }
    float (*h1T)[68] = (float(*)[68])(smem + 10560);
    float* distR = smem + 17360;
    float* uxR   = smem + 17424;
    float* uyR   = smem + 17488;
    float* obR   = smem + 17552;
    float* lgS   = smem + 17616;
    float* nllS  = smem + 17680;
    // preload epilogue weights
    int cg = tid & 7, rg = tid >> 3;
    float b2v[8], w3v[8];
    #pragma unroll
    for (int k = 0; k < 8; k++) {
        int n = (cg << 3) + k;
        b2v[k] = (n < H2) ? om_b2[n] : 0.f;
        w3v[k] = (n < H2) ? om_W3[n] : 0.f;
    }
    float ob2s = ob_b2[0];
    float obz = ws[OFF_OBZ];
    __syncthreads();
    for (int qh = 0; qh < 2; qh++) {
        // features for 64 rows (8 queries x 8 nbrs)
        if (tid < 64) {
            int ql = tid >> 3, d = tid & 7;
            int qa = (qh << 3) + ql;
            int t = t0 + qa;
            int bt = b * TT + t;
            int v = xs[bt];
            int a = adj[v * DEG + d];
            float nbx = locations[2 * a], nby = locations[2 * a + 1];
            int dst = destinations[b];
            float dxl = locations[2 * dst], dyl = locations[2 * dst + 1];
            float cxl = locations[2 * v], cyl = locations[2 * v + 1];
            distR[tid] = (fabsf(nbx - dxl) + fabsf(nby - dyl)) * 100.f;
            float vx = nbx - cxl, vy = nby - cyl;
            float nrm = sqrtf(vx * vx + vy * vy) + 1e-8f;
            uxR[tid] = vx / nrm; uyR[tid] = vy / nrm;
            float ttn = (ws[OFF_TT + (size_t)bt * 8 + d] - smean) * sdinv;
            float obp = 0.f;
            for (int j = 0; j < 25; j++)
                obp += fmaxf(ttn * ws[OFF_V25 + j] + ws[OFF_C25 + j], 0.f) * ob_W2[j];
            obR[tid] = (a != 0) ? (obp + ob2s) : obz;
        }
        __syncthreads();
        // h1T fill: thread covers row r = tid&63, m range by mq = tid>>6
        {
            int r = tid & 63, mq = tid >> 6;
            int qa = (qh << 3) + (r >> 3);
            float dv = distR[r], ux = uxR[r], uy = uyR[r];
            const float* CD = ws + OFF_CDIST;
            const float* CX = ws + OFF_CDIRX;
            const float* CY = ws + OFF_CDIRY;
            const float* Hq = S[qa];
            int m0 = mq * 25;
            #pragma unroll 5
            for (int mi = 0; mi < 25; mi++) {
                int m = m0 + mi;
                float pre = Hq[m] + dv * CD[m] + ux * CX[m] + uy * CY[m];
                h1T[m][r] = fmaxf(pre, 0.f);
            }
        }
        __syncthreads();
        // GEMM: 64 rows x 50 cols; thread = (rg 0..31 -> 2 rows, cg 0..7 -> 8 cols)
        {
            float facc[2][8];
            #pragma unroll
            for (int jr = 0; jr < 2; jr++)
                #pragma unroll
                for (int k = 0; k < 8; k++) facc[jr][k] = 0.f;
            int r0 = rg << 1, n0 = cg << 3;
            #pragma unroll 4
            for (int m = 0; m < HID; m++) {
                float2 hv = *(const float2*)&h1T[m][r0];
                float4 w0 = *(const float4*)&W2s[m][n0];
                float4 w1 = *(const float4*)&W2s[m][n0 + 4];
                facc[0][0] += hv.x * w0.x; facc[0][1] += hv.x * w0.y;
                facc[0][2] += hv.x * w0.z; facc[0][3] += hv.x * w0.w;
                facc[0][4] += hv.x * w1.x; facc[0][5] += hv.x * w1.y;
                facc[0][6] += hv.x * w1.z; facc[0][7] += hv.x * w1.w;
                facc[1][0] += hv.y * w0.x; facc[1][1] += hv.y * w0.y;
                facc[1][2] += hv.y * w0.z; facc[1][3] += hv.y * w0.w;
                facc[1][4] += hv.y * w1.x; facc[1][5] += hv.y * w1.y;
                facc[1][6] += hv.y * w1.z; facc[1][7] += hv.y * w1.w;
            }
            #pragma unroll
            for (int jr = 0; jr < 2; jr++) {
                float part = 0.f;
                #pragma unroll
                for (int k = 0; k < 8; k++)
                    part += fmaxf(facc[jr][k] + b2v[k], 0.f) * w3v[k];
                part += __shfl_xor(part, 1, 64);
                part += __shfl_xor(part, 2, 64);
                part += __shfl_xor(part, 4, 64);
                if (cg == 0) {
                    int row = r0 + jr;
                    lgS[row] = part + om_b3[0] + obR[row];
                }
            }
        }
        __syncthreads();
        // CE for this half's queries
        if (tid < 8) {
            int qa = (qh << 3) + tid;
            if (qa < nqv) {
                int t = t0 + qa;
                float lg[8];
                float mxl = -1e30f;
                #pragma unroll
                for (int d = 0; d < 8; d++) {
                    lg[d] = lgS[(tid << 3) + d];
                    mxl = fmaxf(mxl, lg[d]);
                }
                int act = xs_actions[b * (TT - 1) + t];
                float se = 0.f, sel = 0.f;
                #pragma unroll
                for (int d = 0; d < 8; d++) {
                    se += __expf(lg[d] - mxl);
                    if (d == act) sel = lg[d];
                }
                float nll = mxl + __logf(se) - sel;
                nllS[qa] = nll / (float)(len - 1);
            }
        }
        __syncthreads();
    }
    if (tid == 0) {
        float s = 0.f;
        #pragma unroll
        for (int i = 0; i < 16; i++) s += nllS[i];
        atomicAdd(out, s);
    }
}

extern "C" void kernel_launch(void* const* d_in, const int* in_sizes, int n_in,
                              void* d_out, int out_size, void* d_ws, size_t ws_size,
                              hipStream_t stream) {
    const int* xs_padded    = (const int*)d_in[0];
    const int* lengths      = (const int*)d_in[1];
    const int* xs_actions   = (const int*)d_in[2];
    const int* destinations = (const int*)d_in[3];
    const int* adj_list     = (const int*)d_in[4];
    const int* seg_ids      = (const int*)d_in[5];
    const int* start_time   = (const int*)d_in[6];
    const float* locations  = (const float*)d_in[7];
    const float* tds        = (const float*)d_in[8];
    const float* emb        = (const float*)d_in[9];
    const float* Wq         = (const float*)d_in[10];
    const float* Wk         = (const float*)d_in[11];
    const float* Wv         = (const float*)d_in[12];
    const float* Wo         = (const float*)d_in[13];
    const float* dist_W     = (const float*)d_in[14];
    const float* dist_b     = (const float*)d_in[15];
    const float* dir_W      = (const float*)d_in[16];
    const float* dir_b      = (const float*)d_in[17];
    const float* tt_W       = (const float*)d_in[18];
    const float* tt_b       = (const float*)d_in[19];
    const float* ob_W1      = (const float*)d_in[20];
    const float* ob_b1      = (const float*)d_in[21];
    const float* ob_W2      = (const float*)d_in[22];
    const float* ob_b2      = (const float*)d_in[23];
    const float* om_W1      = (const float*)d_in[24];
    const float* om_b1      = (const float*)d_in[25];
    const float* om_W2      = (const float*)d_in[26];
    const float* om_b2      = (const float*)d_in[27];
    const float* om_W3      = (const float*)d_in[28];
    const float* om_b3      = (const float*)d_in[29];
    float* ws  = (float*)d_ws;
    float* out = (float*)d_out;

    k_setup<<<193, 256, 0, stream>>>(destinations, emb, Wo, dist_W, dist_b,
                                     dir_W, dir_b, tt_W, tt_b, ob_W1, ob_b1,
                                     ob_W2, ob_b2, om_W1, om_b1, ws, out);
    k_mid<<<768, 256, 0, stream>>>(xs_padded, lengths, adj_list, seg_ids,
                                   start_time, tds, emb, Wq, Wk, Wv, ws);
    k_attnfinal<<<BB * 16, 256, 0, stream>>>(
        lengths, xs_padded, xs_actions, destinations, adj_list, locations,
        om_W2, om_b2, om_W3, om_b3, ob_W2, ob_b2, ws, out);
}

// Round 5
// 444.681 us; speedup vs baseline: 1.3893x; 1.0602x over previous
//
#include <hip/hip_runtime.h>
#include <math.h>

#define BB 64
#define TT 256
#define DEG 8
#define EE 128
#define NBUCKET 288
#define HID 100
#define H2 50

// ---------------- workspace layout (floats) ----------------
constexpr size_t OFF_STATS   = 0;        // 4: sum, sumsq, cnt, pad
constexpr size_t OFF_CDIST   = 4;        // 100
constexpr size_t OFF_CDIRX   = 104;      // 100
constexpr size_t OFF_CDIRY   = 204;      // 100
constexpr size_t OFF_BASE    = 304;      // 100
constexpr size_t OFF_V25     = 404;      // 25
constexpr size_t OFF_C25     = 429;      // 25
constexpr size_t OFF_OBZ     = 454;      // 1
constexpr size_t OFF_DESTPRE = 456;      // 64*100
constexpr size_t OFF_WF      = 6856;     // 128*100 (Wo @ om_W1[0:128])
constexpr size_t OFF_TT      = 32456;    // 16384*8 travel times
constexpr size_t OFF_Q       = 163528;   // 16384*128
constexpr size_t OFF_K       = OFF_Q + 16384 * 128;
constexpr size_t OFF_VP      = OFF_K + 16384 * 128;   // 16384*100

// ---------------- setup: prevec (blk 0) + destpre (1..64) + wfused (65..192) ----------------
__global__ void __launch_bounds__(256) k_setup(
    const int* destinations, const float* emb, const float* Wo,
    const float* dist_W, const float* dist_b, const float* dir_W, const float* dir_b,
    const float* tt_W, const float* tt_b, const float* ob_W1, const float* ob_b1,
    const float* ob_W2, const float* ob_b2, const float* om_W1, const float* om_b1,
    float* ws, float* out) {
    __shared__ float sh[EE];
    int blk = blockIdx.x;
    int j = threadIdx.x;
    if (blk == 0) {
        if (j < 4) ws[OFF_STATS + j] = 0.f;
        if (j == 0) out[0] = 0.f;
        if (j < HID) {
            float cd = 0.f, cx = 0.f, cy = 0.f, bs = om_b1[j];
            for (int f = 0; f < 50; f++) {
                float w1d = om_W1[(128 + f) * HID + j];
                float w1r = om_W1[(178 + f) * HID + j];
                cd += dist_W[f] * w1d;
                bs += dist_b[f] * w1d + dir_b[f] * w1r;
                cx += dir_W[f] * w1r;
                cy += dir_W[50 + f] * w1r;
            }
            ws[OFF_CDIST + j] = cd; ws[OFF_CDIRX + j] = cx;
            ws[OFF_CDIRY + j] = cy; ws[OFF_BASE + j] = bs;
        }
        if (j >= 128 && j < 153) {
            int jj = j - 128;
            float v = 0.f, c = ob_b1[jj];
            for (int i = 0; i < 50; i++) {
                v += tt_W[i] * ob_W1[i * 25 + jj];
                c += tt_b[i] * ob_W1[i * 25 + jj];
            }
            ws[OFF_V25 + jj] = v; ws[OFF_C25 + jj] = c;
        }
        if (j == 200) {
            float z = ob_b2[0];
            for (int i = 0; i < 25; i++) z += fmaxf(ob_b1[i], 0.f) * ob_W2[i];
            ws[OFF_OBZ] = z;
        }
    } else if (blk <= 64) {
        int b = blk - 1;
        if (j < EE) sh[j] = emb[(size_t)destinations[b] * EE + j];
        __syncthreads();
        if (j < HID) {
            float acc = 0.f;
            for (int i = 0; i < EE; i++) acc += sh[i] * om_W1[(228 + i) * HID + j];
            ws[OFF_DESTPRE + b * HID + j] = acc;
        }
    } else {
        int i = blk - 65;
        if (j < EE) sh[j] = Wo[i * EE + j];
        __syncthreads();
        if (j < HID) {
            float acc = 0.f;
            for (int jj = 0; jj < EE; jj++) acc += sh[jj] * om_W1[jj * HID + j];
            ws[OFF_WF + i * HID + j] = acc;
        }
    }
}

// ---------------- mid: QKV' GEMM (blocks 0..511) + whitening stats (512..767) ----------------
__global__ void __launch_bounds__(256) k_mid(
    const int* xs, const int* lengths, const int* adj, const int* seg,
    const int* stime, const float* tds, const float* emb,
    const float* Wq, const float* Wk, const float* Wv, float* ws) {
    __shared__ float smem[2 * 128 * 36 + 32];
    int blk = blockIdx.x;
    int tid = threadIdx.x;
    if (blk < 512) {
        float (*XT)[36]  = (float(*)[36])smem;
        float (*T1T)[36] = (float(*)[36])(smem + 128 * 36);
        int* vids = (int*)(smem + 2 * 128 * 36);
        int r0 = blk * 32;
        if (tid < 32) vids[tid] = xs[r0 + tid];
        __syncthreads();
        for (int c = 0; c < 16; c++) {
            int idx = c * 256 + tid;
            int r = idx >> 7, i = idx & 127;
            XT[i][r] = emb[(size_t)vids[r] * EE + i];
        }
        __syncthreads();
        int cg = tid & 31, rg = tid >> 5;
        const float* Wmats[2] = {Wq, Wk};
        float* Omats[2] = {ws + OFF_Q, ws + OFF_K};
        for (int mtx = 0; mtx < 2; mtx++) {
            const float* W = Wmats[mtx];
            float acc[4][4];
            #pragma unroll
            for (int a = 0; a < 4; a++)
                #pragma unroll
                for (int bb = 0; bb < 4; bb++) acc[a][bb] = 0.f;
            #pragma unroll 4
            for (int i = 0; i < EE; i++) {
                float4 av = *(const float4*)&XT[i][rg << 2];
                float4 wv = *(const float4*)&W[i * EE + (cg << 2)];
                acc[0][0] += av.x * wv.x; acc[0][1] += av.x * wv.y; acc[0][2] += av.x * wv.z; acc[0][3] += av.x * wv.w;
                acc[1][0] += av.y * wv.x; acc[1][1] += av.y * wv.y; acc[1][2] += av.y * wv.z; acc[1][3] += av.y * wv.w;
                acc[2][0] += av.z * wv.x; acc[2][1] += av.z * wv.y; acc[2][2] += av.z * wv.z; acc[2][3] += av.z * wv.w;
                acc[3][0] += av.w * wv.x; acc[3][1] += av.w * wv.y; acc[3][2] += av.w * wv.z; acc[3][3] += av.w * wv.w;
            }
            float* O = Omats[mtx];
            #pragma unroll
            for (int jj = 0; jj < 4; jj++)
                *(float4*)&O[(size_t)(r0 + (rg << 2) + jj) * EE + (cg << 2)] =
                    make_float4(acc[jj][0], acc[jj][1], acc[jj][2], acc[jj][3]);
        }
        // T1 = X @ Wv, transposed into LDS
        {
            float acc[4][4];
            #pragma unroll
            for (int a = 0; a < 4; a++)
                #pragma unroll
                for (int bb = 0; bb < 4; bb++) acc[a][bb] = 0.f;
            #pragma unroll 4
            for (int i = 0; i < EE; i++) {
                float4 av = *(const float4*)&XT[i][rg << 2];
                float4 wv = *(const float4*)&Wv[i * EE + (cg << 2)];
                acc[0][0] += av.x * wv.x; acc[0][1] += av.x * wv.y; acc[0][2] += av.x * wv.z; acc[0][3] += av.x * wv.w;
                acc[1][0] += av.y * wv.x; acc[1][1] += av.y * wv.y; acc[1][2] += av.y * wv.z; acc[1][3] += av.y * wv.w;
                acc[2][0] += av.z * wv.x; acc[2][1] += av.z * wv.y; acc[2][2] += av.z * wv.z; acc[2][3] += av.z * wv.w;
                acc[3][0] += av.w * wv.x; acc[3][1] += av.w * wv.y; acc[3][2] += av.w * wv.z; acc[3][3] += av.w * wv.w;
            }
            #pragma unroll
            for (int jj = 0; jj < 4; jj++)
                #pragma unroll
                for (int ii = 0; ii < 4; ii++)
                    T1T[(cg << 2) + ii][(rg << 2) + jj] = acc[jj][ii];
        }
        __syncthreads();
        if (cg < 25) {
            const float* WF = ws + OFF_WF;
            float acc[4][4];
            #pragma unroll
            for (int a = 0; a < 4; a++)
                #pragma unroll
                for (int bb = 0; bb < 4; bb++) acc[a][bb] = 0.f;
            #pragma unroll 4
            for (int i = 0; i < EE; i++) {
                float4 av = *(const float4*)&T1T[i][rg << 2];
                float4 wv = *(const float4*)&WF[i * HID + (cg << 2)];
                acc[0][0] += av.x * wv.x; acc[0][1] += av.x * wv.y; acc[0][2] += av.x * wv.z; acc[0][3] += av.x * wv.w;
                acc[1][0] += av.y * wv.x; acc[1][1] += av.y * wv.y; acc[1][2] += av.y * wv.z; acc[1][3] += av.y * wv.w;
                acc[2][0] += av.z * wv.x; acc[2][1] += av.z * wv.y; acc[2][2] += av.z * wv.z; acc[2][3] += av.z * wv.w;
                acc[3][0] += av.w * wv.x; acc[3][1] += av.w * wv.y; acc[3][2] += av.w * wv.z; acc[3][3] += av.w * wv.w;
            }
            float* VP = ws + OFF_VP;
            #pragma unroll
            for (int jj = 0; jj < 4; jj++)
                *(float4*)&VP[(size_t)(r0 + (rg << 2) + jj) * HID + (cg << 2)] =
                    make_float4(acc[jj][0], acc[jj][1], acc[jj][2], acc[jj][3]);
        }
    } else {
        // ---- stats ----
        float* rs = smem; float* rq = smem + 256; float* rc = smem + 512;
        int st = *stime;
        float lsum = 0.f, lsq = 0.f, lcnt = 0.f;
        int total = BB * TT * DEG;
        for (int idx = (blk - 512) * 256 + tid; idx < total; idx += 256 * 256) {
            int d = idx & 7;
            int bt = idx >> 3;
            int t = bt & 255;
            int b = bt >> 8;
            int len = lengths[b];
            if (t >= len - 1) continue;
            int v = xs[bt];
            int sg = seg[v * DEG + d];
            float tt = tds[(size_t)sg * NBUCKET + st];
            ws[OFF_TT + idx] = tt;
            int a = adj[v * DEG + d];
            if (a != 0) { lsum += tt; lsq += tt * tt; lcnt += 1.f; }
        }
        rs[tid] = lsum; rq[tid] = lsq; rc[tid] = lcnt;
        __syncthreads();
        for (int s = 128; s > 0; s >>= 1) {
            if (tid < s) { rs[tid] += rs[tid + s]; rq[tid] += rq[tid + s]; rc[tid] += rc[tid + s]; }
            __syncthreads();
        }
        if (tid == 0) {
            atomicAdd(&ws[OFF_STATS + 0], rs[0]);
            atomicAdd(&ws[OFF_STATS + 1], rq[0]);
            atomicAdd(&ws[OFF_STATS + 2], rc[0]);
        }
    }
}

// ---------------- fused attention + neighbor-MLP + CE: 8 queries/block ----------------
// LDS (floats, total 13160 = 51.4 KB -> 3 blocks/CU):
//   H1P[8][104]          @0      (832)   persists A->B
//   phase A union @832:
//     Qs[8][132]         @832    (1056)
//     S [8][260]         @1888   (2080)
//     Vs[64][104]        @3968   (6656)
//     pacc[128][8]       @10624  (1024)
//   phase B union @832:
//     W2s[100][56]       @832    (5600)
//     h1T[100][64]       @6432   (6400)
//   feats @12832: distR/uxR/uyR/obR[64] (256) | lgS[64] @13088 | nllS[8] @13152
__global__ void __launch_bounds__(256) k_attnfinal(
    const int* lengths, const int* xs, const int* xs_actions,
    const int* destinations, const int* adj, const float* locations,
    const float* om_W2, const float* om_b2, const float* om_W3, const float* om_b3,
    const float* ob_W2, const float* ob_b2,
    float* ws, float* out) {
    int blk = blockIdx.x;
    int tile = 31 - (blk >> 6);          // long tiles dispatch first
    int b = blk & 63;
    int t0 = tile << 3;
    int len = lengths[b];
    if (t0 >= len - 1) return;
    int nqv = len - 1 - t0; if (nqv > 8) nqv = 8;
    int nk = t0 + 8;
    __shared__ float smem[13160];
    float (*H1P)[104] = (float(*)[104])smem;
    float (*Qs)[132]  = (float(*)[132])(smem + 832);
    float (*S)[260]   = (float(*)[260])(smem + 1888);
    float (*Vs)[104]  = (float(*)[104])(smem + 3968);
    float (*pacc)[8]  = (float(*)[8])(smem + 10624);
    float (*W2s)[56]  = (float(*)[56])(smem + 832);
    float (*h1T)[64]  = (float(*)[64])(smem + 6432);
    float* distR = smem + 12832;
    float* uxR   = smem + 12896;
    float* uyR   = smem + 12960;
    float* obR   = smem + 13024;
    float* lgS   = smem + 13088;
    float* nllS  = smem + 13152;
    int tid = threadIdx.x;
    if (tid < 8) nllS[tid] = 0.f;
    // ---- stage Q (8 rows x 128) ----
    {
        const float* Qg = ws + OFF_Q + (size_t)(b * TT + t0) * EE;
        int r = tid >> 5, c4 = (tid & 31) << 2;
        *(float4*)&Qs[r][c4] = *(const float4*)&Qg[r * EE + c4];
    }
    __syncthreads();
    // ---- scores: wave owns 16 keys as register fragments, K from global/L2 ----
    {
        const float* Kg = ws + OFF_K + (size_t)(b * TT) * EE;
        int w = tid >> 6;
        int key = (tid >> 2) & 15, chunk = tid & 3;
        int coff = chunk << 5;
        for (int k0 = w << 4; k0 < nk; k0 += 64) {
            int kk = k0 + key;
            if (kk < nk) {
                float4 kf[8];
                const float4* Kr = (const float4*)&Kg[(size_t)kk * EE + coff];
                #pragma unroll
                for (int j = 0; j < 8; j++) kf[j] = Kr[j];
                #pragma unroll
                for (int q = 0; q < 8; q++) {
                    const float4* qr = (const float4*)&Qs[q][coff];
                    float s = 0.f;
                    #pragma unroll
                    for (int j = 0; j < 8; j++) {
                        float4 a = qr[j], x = kf[j];
                        s += a.x * x.x + a.y * x.y + a.z * x.z + a.w * x.w;
                    }
                    s += __shfl_xor(s, 1, 64);
                    s += __shfl_xor(s, 2, 64);
                    if (chunk == 0) S[q][kk] = s * 0.08838834764831845f;
                }
            }
        }
    }
    __syncthreads();
    // ---- softmax: 16 lanes per query ----
    if (tid < 128) {
        int q = tid >> 4, li = tid & 15;
        int tq = t0 + q;
        float sreg[16];
        float mx = -1e30f;
        #pragma unroll
        for (int m = 0; m < 16; m++) {
            int k = li + (m << 4);
            float sv = (k < nk && k <= tq) ? S[q][k] : -1e30f;
            sreg[m] = sv;
            mx = fmaxf(mx, sv);
        }
        #pragma unroll
        for (int o = 1; o < 16; o <<= 1) mx = fmaxf(mx, __shfl_xor(mx, o, 16));
        float ls = 0.f;
        #pragma unroll
        for (int m = 0; m < 16; m++) {
            float p = __expf(sreg[m] - mx);
            sreg[m] = p; ls += p;
        }
        #pragma unroll
        for (int o = 1; o < 16; o <<= 1) ls += __shfl_xor(ls, o, 16);
        float inv = 1.f / ls;
        #pragma unroll
        for (int m = 0; m < 16; m++) S[q][li + (m << 4)] = sreg[m] * inv;
    }
    __syncthreads();
    // ---- PV: threads (kc half, q, cg) 8-col float4 tiles; key-split, LDS merge ----
    {
        int kc = tid >> 7;
        int q = (tid >> 4) & 7, cg = tid & 15;
        float acc[8];
        #pragma unroll
        for (int j = 0; j < 8; j++) acc[j] = 0.f;
        const float* VPg = ws + OFF_VP + (size_t)(b * TT) * HID;
        for (int vt0 = 0; vt0 < nk; vt0 += 64) {
            __syncthreads();
            int nrow = nk - vt0; if (nrow > 64) nrow = 64;
            for (int idx = tid; idx < nrow * 25; idx += 256) {
                int r = idx / 25, c4 = (idx - r * 25) << 2;
                *(float4*)&Vs[r][c4] = *(const float4*)&VPg[(size_t)(vt0 + r) * HID + c4];
            }
            __syncthreads();
            int base = vt0 + (kc << 5);
            int kmax = nk - base; if (kmax > 32) kmax = 32;
            if (cg < 13) {
                for (int k = 0; k < kmax; k++) {
                    float p = S[q][base + k];
                    const float4* vr = (const float4*)&Vs[(kc << 5) + k][cg << 3];
                    float4 v0 = vr[0], v1 = vr[1];
                    acc[0] += p * v0.x; acc[1] += p * v0.y;
                    acc[2] += p * v0.z; acc[3] += p * v0.w;
                    acc[4] += p * v1.x; acc[5] += p * v1.y;
                    acc[6] += p * v1.z; acc[7] += p * v1.w;
                }
            }
        }
        if (kc == 1 && cg < 13) {
            float* pp = pacc[(q << 4) + cg];
            #pragma unroll
            for (int j = 0; j < 8; j++) pp[j] = acc[j];
        }
        __syncthreads();
        if (kc == 0 && cg < 13) {
            const float* pp = pacc[(q << 4) + cg];
            const float* BASEv = ws + OFF_BASE;
            const float* DP = ws + OFF_DESTPRE + b * HID;
            int c0 = cg << 3;
            #pragma unroll
            for (int j = 0; j < 8; j++) {
                int c = c0 + j;
                if (c < HID) H1P[q][c] = acc[j] + pp[j] + BASEv[c] + DP[c];
            }
        }
    }
    __syncthreads();
    // ---- phase B: stage W2s, features, h1T, GEMM, CE ----
    for (int idx = tid; idx < 5600; idx += 256) {
        int mm = idx / 56, n = idx - mm * 56;
        W2s[mm][n] = (n < H2) ? om_W2[mm * H2 + n] : 0.f;
    }
    float smean, sdinv;
    {
        float sum = ws[OFF_STATS], sq = ws[OFF_STATS + 1], cnt = ws[OFF_STATS + 2];
        smean = sum / cnt;
        float var = (sq - cnt * smean * smean) / (cnt - 1.f);
        sdinv = 1.f / (sqrtf(var) + 1e-6f);
    }
    if (tid < 64) {
        int ql = tid >> 3, d = tid & 7;
        int t = t0 + ql;
        int bt = b * TT + t;
        int v = xs[bt];
        int a = adj[v * DEG + d];
        float nbx = locations[2 * a], nby = locations[2 * a + 1];
        int dst = destinations[b];
        float dxl = locations[2 * dst], dyl = locations[2 * dst + 1];
        float cxl = locations[2 * v], cyl = locations[2 * v + 1];
        distR[tid] = (fabsf(nbx - dxl) + fabsf(nby - dyl)) * 100.f;
        float vx = nbx - cxl, vy = nby - cyl;
        float nrm = sqrtf(vx * vx + vy * vy) + 1e-8f;
        uxR[tid] = vx / nrm; uyR[tid] = vy / nrm;
        float ttn = (ws[OFF_TT + (size_t)bt * 8 + d] - smean) * sdinv;
        float obp = 0.f;
        for (int j = 0; j < 25; j++)
            obp += fmaxf(ttn * ws[OFF_V25 + j] + ws[OFF_C25 + j], 0.f) * ob_W2[j];
        obR[tid] = (a != 0) ? (obp + ob_b2[0]) : ws[OFF_OBZ];
    }
    __syncthreads();
    {
        int r = tid & 63, mq = tid >> 6;
        int qa = r >> 3;
        float dv = distR[r], ux = uxR[r], uy = uyR[r];
        const float* CD = ws + OFF_CDIST;
        const float* CX = ws + OFF_CDIRX;
        const float* CY = ws + OFF_CDIRY;
        const float* Hq = H1P[qa];
        int m0 = mq * 25;
        #pragma unroll 5
        for (int mi = 0; mi < 25; mi++) {
            int m = m0 + mi;
            float pre = Hq[m] + dv * CD[m] + ux * CX[m] + uy * CY[m];
            h1T[m][r] = fmaxf(pre, 0.f);
        }
    }
    __syncthreads();
    if (tid < 128) {
        int rg = tid >> 3, cg = tid & 7;   // rg 0..15 (4 rows each), cg 0..7 (cg==7 idle)
        int r0 = rg << 2, n0 = cg << 3;
        float parts[4] = {0.f, 0.f, 0.f, 0.f};
        if (cg < 7) {
            float facc[4][8];
            #pragma unroll
            for (int jr = 0; jr < 4; jr++)
                #pragma unroll
                for (int k = 0; k < 8; k++) facc[jr][k] = 0.f;
            #pragma unroll 4
            for (int m = 0; m < HID; m++) {
                float4 hv = *(const float4*)&h1T[m][r0];
                float4 w0 = *(const float4*)&W2s[m][n0];
                float4 w1 = *(const float4*)&W2s[m][n0 + 4];
                facc[0][0] += hv.x * w0.x; facc[0][1] += hv.x * w0.y; facc[0][2] += hv.x * w0.z; facc[0][3] += hv.x * w0.w;
                facc[0][4] += hv.x * w1.x; facc[0][5] += hv.x * w1.y; facc[0][6] += hv.x * w1.z; facc[0][7] += hv.x * w1.w;
                facc[1][0] += hv.y * w0.x; facc[1][1] += hv.y * w0.y; facc[1][2] += hv.y * w0.z; facc[1][3] += hv.y * w0.w;
                facc[1][4] += hv.y * w1.x; facc[1][5] += hv.y * w1.y; facc[1][6] += hv.y * w1.z; facc[1][7] += hv.y * w1.w;
                facc[2][0] += hv.z * w0.x; facc[2][1] += hv.z * w0.y; facc[2][2] += hv.z * w0.z; facc[2][3] += hv.z * w0.w;
                facc[2][4] += hv.z * w1.x; facc[2][5] += hv.z * w1.y; facc[2][6] += hv.z * w1.z; facc[2][7] += hv.z * w1.w;
                facc[3][0] += hv.w * w0.x; facc[3][1] += hv.w * w0.y; facc[3][2] += hv.w * w0.z; facc[3][3] += hv.w * w0.w;
                facc[3][4] += hv.w * w1.x; facc[3][5] += hv.w * w1.y; facc[3][6] += hv.w * w1.z; facc[3][7] += hv.w * w1.w;
            }
            float b2v[8], w3v[8];
            #pragma unroll
            for (int k = 0; k < 8; k++) {
                int n = n0 + k;
                b2v[k] = (n < H2) ? om_b2[n] : 0.f;
                w3v[k] = (n < H2) ? om_W3[n] : 0.f;
            }
            #pragma unroll
            for (int jr = 0; jr < 4; jr++) {
                float part = 0.f;
                #pragma unroll
                for (int k = 0; k < 8; k++)
                    part += fmaxf(facc[jr][k] + b2v[k], 0.f) * w3v[k];
                parts[jr] = part;
            }
        }
        float ob3 = om_b3[0];
        #pragma unroll
        for (int jr = 0; jr < 4; jr++) {
            float part = parts[jr];
            part += __shfl_xor(part, 1, 64);
            part += __shfl_xor(part, 2, 64);
            part += __shfl_xor(part, 4, 64);
            if (cg == 0) lgS[r0 + jr] = part + ob3 + obR[r0 + jr];
        }
    }
    __syncthreads();
    if (tid < 8) {
        int qa = tid;
        if (qa < nqv) {
            float lg[8];
            float mxl = -1e30f;
            #pragma unroll
            for (int d = 0; d < 8; d++) {
                lg[d] = lgS[(qa << 3) + d];
                mxl = fmaxf(mxl, lg[d]);
            }
            int act = xs_actions[b * (TT - 1) + t0 + qa];
            float se = 0.f, sel = 0.f;
            #pragma unroll
            for (int d = 0; d < 8; d++) {
                se += __expf(lg[d] - mxl);
                if (d == act) sel = lg[d];
            }
            float nll = mxl + __logf(se) - sel;
            nllS[qa] = nll / (float)(len - 1);
        }
    }
    __syncthreads();
    if (tid == 0) {
        float s = 0.f;
        #pragma unroll
        for (int i = 0; i < 8; i++) s += nllS[i];
        atomicAdd(out, s);
    }
}

extern "C" void kernel_launch(void* const* d_in, const int* in_sizes, int n_in,
                              void* d_out, int out_size, void* d_ws, size_t ws_size,
                              hipStream_t stream) {
    const int* xs_padded    = (const int*)d_in[0];
    const int* lengths      = (const int*)d_in[1];
    const int* xs_actions   = (const int*)d_in[2];
    const int* destinations = (const int*)d_in[3];
    const int* adj_list     = (const int*)d_in[4];
    const int* seg_ids      = (const int*)d_in[5];
    const int* start_time   = (const int*)d_in[6];
    const float* locations  = (const float*)d_in[7];
    const float* tds        = (const float*)d_in[8];
    const float* emb        = (const float*)d_in[9];
    const float* Wq         = (const float*)d_in[10];
    const float* Wk         = (const float*)d_in[11];
    const float* Wv         = (const float*)d_in[12];
    const float* Wo         = (const float*)d_in[13];
    const float* dist_W     = (const float*)d_in[14];
    const float* dist_b     = (const float*)d_in[15];
    const float* dir_W      = (const float*)d_in[16];
    const float* dir_b      = (const float*)d_in[17];
    const float* tt_W       = (const float*)d_in[18];
    const float* tt_b       = (const float*)d_in[19];
    const float* ob_W1      = (const float*)d_in[20];
    const float* ob_b1      = (const float*)d_in[21];
    const float* ob_W2      = (const float*)d_in[22];
    const float* ob_b2      = (const float*)d_in[23];
    const float* om_W1      = (const float*)d_in[24];
    const float* om_b1      = (const float*)d_in[25];
    const float* om_W2      = (const float*)d_in[26];
    const float* om_b2      = (const float*)d_in[27];
    const float* om_W3      = (const float*)d_in[28];
    const float* om_b3      = (const float*)d_in[29];
    float* ws  = (float*)d_ws;
    float* out = (float*)d_out;

    k_setup<<<193, 256, 0, stream>>>(destinations, emb, Wo, dist_W, dist_b,
                                     dir_W, dir_b, tt_W, tt_b, ob_W1, ob_b1,
                                     ob_W2, ob_b2, om_W1, om_b1, ws, out);
    k_mid<<<768, 256, 0, stream>>>(xs_padded, lengths, adj_list, seg_ids,
                                   start_time, tds, emb, Wq, Wk, Wv, ws);
    k_attnfinal<<<BB * 32, 256, 0, stream>>>(
        lengths, xs_padded, xs_actions, destinations, adj_list, locations,
        om_W2, om_b2, om_W3, om_b3, ob_W2, ob_b2, ws, out);
}